// Round 3
// baseline (737.063 us; speedup 1.0000x reference)
//
#include <hip/hip_runtime.h>
#include <hip/hip_bf16.h>

#define DIN 2048
#define DOUT 2048
#define NTOK 16384   // B*S = 4*4096

typedef __bf16 bf16x8 __attribute__((ext_vector_type(8)));
typedef float f32x4 __attribute__((ext_vector_type(4)));

__device__ __forceinline__ void load_lds16(const void* g, void* l) {
  __builtin_amdgcn_global_load_lds((const __attribute__((address_space(1))) void*)g,
                                   (__attribute__((address_space(3))) void*)l,
                                   16, 0, 0);
}

__device__ __forceinline__ void store1(float* p, float v) { *p = v; }
__device__ __forceinline__ void store1(__hip_bfloat16* p, float v) { *p = __float2bfloat16(v); }

// ---------------------------------------------------------------------------
// C[m][n] = (sum_k A[m][k]*B[n][k]) * colf[n]    (B^T GEMM, bf16 in, fp32 acc)
// m97 structure: 128x128 tile, BK=32, 4 waves each 64x64 (4x4 frags of 16x16)
// ---------------------------------------------------------------------------
template <typename OutT>
__global__ __launch_bounds__(256) void gemm_bt(
    const __hip_bfloat16* __restrict__ A,
    const __hip_bfloat16* __restrict__ B,
    OutT* __restrict__ C,
    const float* __restrict__ colf,
    int M, int N, int K)
{
  constexpr int BK = 32;
  __shared__ __hip_bfloat16 lA[128 * BK];
  __shared__ __hip_bfloat16 lB[128 * BK];
  const int t = threadIdx.x;
  const int lane = t & 63;
  const int wid = t >> 6;
  const int wr = wid >> 1, wc = wid & 1;
  const int nbn = N / 128;
  const long m0 = (long)(blockIdx.x / nbn) * 128;
  const long n0 = (long)(blockIdx.x % nbn) * 128;

  const int offB = t * 16;            // byte offset in 8192-byte tile
  const int row0 = offB >> 6;         // 64 bytes per row (BK*2)
  const int cole = (offB & 63) >> 1;  // element offset within row

  const __hip_bfloat16* gA0 = A + (m0 + row0) * (long)K + cole;
  const __hip_bfloat16* gA1 = gA0 + 64L * K;
  const __hip_bfloat16* gB0 = B + (n0 + row0) * (long)K + cole;
  const __hip_bfloat16* gB1 = gB0 + 64L * K;
  __hip_bfloat16* lAp = lA + t * 8;
  __hip_bfloat16* lBp = lB + t * 8;

  f32x4 acc[4][4] = {};

  const int kr = (lane >> 4) * 8;
  const int rA = wr * 64 + (lane & 15);
  const int rB = wc * 64 + (lane & 15);

  for (int k0 = 0; k0 < K; k0 += BK) {
    __syncthreads();
    load_lds16(gA0 + k0, lAp);
    load_lds16(gA1 + k0, lAp + 2048);
    load_lds16(gB0 + k0, lBp);
    load_lds16(gB1 + k0, lBp + 2048);
    __syncthreads();
    bf16x8 af[4], bfr[4];
#pragma unroll
    for (int m = 0; m < 4; ++m)
      af[m] = *(const bf16x8*)(lA + (rA + m * 16) * BK + kr);
#pragma unroll
    for (int n = 0; n < 4; ++n)
      bfr[n] = *(const bf16x8*)(lB + (rB + n * 16) * BK + kr);
#pragma unroll
    for (int m = 0; m < 4; ++m)
#pragma unroll
      for (int n = 0; n < 4; ++n)
        acc[m][n] = __builtin_amdgcn_mfma_f32_16x16x32_bf16(af[m], bfr[n], acc[m][n], 0, 0, 0);
  }

  // C/D layout: col = lane&15, row = (lane>>4)*4 + e
  const int cr = (lane >> 4) * 4;
  const int cc = lane & 15;
#pragma unroll
  for (int m = 0; m < 4; ++m) {
    const long r0 = m0 + wr * 64 + m * 16 + cr;
#pragma unroll
    for (int n = 0; n < 4; ++n) {
      const long col = n0 + wc * 64 + n * 16 + cc;
      const float f = colf[col];
#pragma unroll
      for (int e = 0; e < 4; ++e)
        store1(&C[(r0 + e) * N + col], acc[m][n][e] * f);
    }
  }
}

// ---------------------------------------------------------------------------
// Split-precision GEMM for w_rot = W @ R (both operands hi+lo bf16):
//   acc += Ahi*Bhi + Ahi*Blo + Alo*Bhi   (lo*lo term ~2^-18, dropped)
// Each bf16*bf16 product is exact in the f32 MFMA accumulator -> w_rot error
// ~1e-7, far below the 4-bit quant bin width.
// Tile 128x64, BK=32, 4 waves (2x2), wave tile 64x32 = 4x2 frags.
// ---------------------------------------------------------------------------
__global__ __launch_bounds__(256) void gemm_wsplit(
    const __hip_bfloat16* __restrict__ Ahi, const __hip_bfloat16* __restrict__ Alo,
    const __hip_bfloat16* __restrict__ Bhi, const __hip_bfloat16* __restrict__ Blo,
    float* __restrict__ C,
    const float* __restrict__ colf,
    int M, int N, int K)
{
  constexpr int BK = 32;
  __shared__ __hip_bfloat16 lAhi[128 * BK];
  __shared__ __hip_bfloat16 lAlo[128 * BK];
  __shared__ __hip_bfloat16 lBhi[64 * BK];
  __shared__ __hip_bfloat16 lBlo[64 * BK];
  const int t = threadIdx.x;
  const int lane = t & 63;
  const int wid = t >> 6;
  const int wr = wid >> 1, wc = wid & 1;
  const int nbn = N / 64;
  const long m0 = (long)(blockIdx.x / nbn) * 128;
  const long n0 = (long)(blockIdx.x % nbn) * 64;

  const int offB = t * 16;
  const int row0 = offB >> 6;         // < 64
  const int cole = (offB & 63) >> 1;

  const long aoff = (m0 + row0) * (long)K + cole;
  const long boff = (n0 + row0) * (long)K + cole;
  __hip_bfloat16* lAp = lAhi + t * 8;   // same offset valid for lAlo
  __hip_bfloat16* lBp = lBhi + t * 8;

  f32x4 acc[4][2] = {};

  const int kr = (lane >> 4) * 8;
  const int rA = wr * 64 + (lane & 15);
  const int rB = wc * 32 + (lane & 15);

  for (int k0 = 0; k0 < K; k0 += BK) {
    __syncthreads();
    load_lds16(Ahi + aoff + k0, lAp);
    load_lds16(Ahi + aoff + 64L * K + k0, lAp + 2048);
    load_lds16(Alo + aoff + k0, lAlo + t * 8);
    load_lds16(Alo + aoff + 64L * K + k0, lAlo + t * 8 + 2048);
    load_lds16(Bhi + boff + k0, lBp);
    load_lds16(Blo + boff + k0, lBlo + t * 8);
    __syncthreads();
    bf16x8 ah[4], al[4], bh[2], bl[2];
#pragma unroll
    for (int m = 0; m < 4; ++m) {
      ah[m] = *(const bf16x8*)(lAhi + (rA + m * 16) * BK + kr);
      al[m] = *(const bf16x8*)(lAlo + (rA + m * 16) * BK + kr);
    }
#pragma unroll
    for (int n = 0; n < 2; ++n) {
      bh[n] = *(const bf16x8*)(lBhi + (rB + n * 16) * BK + kr);
      bl[n] = *(const bf16x8*)(lBlo + (rB + n * 16) * BK + kr);
    }
#pragma unroll
    for (int m = 0; m < 4; ++m)
#pragma unroll
      for (int n = 0; n < 2; ++n) {
        acc[m][n] = __builtin_amdgcn_mfma_f32_16x16x32_bf16(ah[m], bh[n], acc[m][n], 0, 0, 0);
        acc[m][n] = __builtin_amdgcn_mfma_f32_16x16x32_bf16(ah[m], bl[n], acc[m][n], 0, 0, 0);
        acc[m][n] = __builtin_amdgcn_mfma_f32_16x16x32_bf16(al[m], bh[n], acc[m][n], 0, 0, 0);
      }
  }

  const int cr = (lane >> 4) * 4;
  const int cc = lane & 15;
#pragma unroll
  for (int m = 0; m < 4; ++m) {
    const long r0 = m0 + wr * 64 + m * 16 + cr;
#pragma unroll
    for (int n = 0; n < 2; ++n) {
      const long col = n0 + wc * 32 + n * 16 + cc;
      const float f = colf[col];
#pragma unroll
      for (int e = 0; e < 4; ++e)
        C[(r0 + e) * N + col] = acc[m][n][e] * f;
    }
  }
}

// ---------------------------------------------------------------------------
// Final GEMM: out[t][o] = (sum_k qh[t][k]*qw[o][k]) * srow[t]*wscale[o] + bias[o]
// qh, qw hold small integers exactly representable in bf16 -> exact result
// ---------------------------------------------------------------------------
__global__ __launch_bounds__(256) void gemm_out(
    const __hip_bfloat16* __restrict__ A,
    const __hip_bfloat16* __restrict__ B,
    float* __restrict__ C,
    const float* __restrict__ srow,
    const float* __restrict__ wscale,
    const float* __restrict__ bias,
    int M, int N, int K)
{
  constexpr int BK = 32;
  __shared__ __hip_bfloat16 lA[128 * BK];
  __shared__ __hip_bfloat16 lB[128 * BK];
  const int t = threadIdx.x;
  const int lane = t & 63;
  const int wid = t >> 6;
  const int wr = wid >> 1, wc = wid & 1;
  const int nbn = N / 128;
  const long m0 = (long)(blockIdx.x / nbn) * 128;
  const long n0 = (long)(blockIdx.x % nbn) * 128;

  const int offB = t * 16;
  const int row0 = offB >> 6;
  const int cole = (offB & 63) >> 1;

  const __hip_bfloat16* gA0 = A + (m0 + row0) * (long)K + cole;
  const __hip_bfloat16* gA1 = gA0 + 64L * K;
  const __hip_bfloat16* gB0 = B + (n0 + row0) * (long)K + cole;
  const __hip_bfloat16* gB1 = gB0 + 64L * K;
  __hip_bfloat16* lAp = lA + t * 8;
  __hip_bfloat16* lBp = lB + t * 8;

  f32x4 acc[4][4] = {};

  const int kr = (lane >> 4) * 8;
  const int rA = wr * 64 + (lane & 15);
  const int rB = wc * 64 + (lane & 15);

  for (int k0 = 0; k0 < K; k0 += BK) {
    __syncthreads();
    load_lds16(gA0 + k0, lAp);
    load_lds16(gA1 + k0, lAp + 2048);
    load_lds16(gB0 + k0, lBp);
    load_lds16(gB1 + k0, lBp + 2048);
    __syncthreads();
    bf16x8 af[4], bfr[4];
#pragma unroll
    for (int m = 0; m < 4; ++m)
      af[m] = *(const bf16x8*)(lA + (rA + m * 16) * BK + kr);
#pragma unroll
    for (int n = 0; n < 4; ++n)
      bfr[n] = *(const bf16x8*)(lB + (rB + n * 16) * BK + kr);
#pragma unroll
    for (int m = 0; m < 4; ++m)
#pragma unroll
      for (int n = 0; n < 4; ++n)
        acc[m][n] = __builtin_amdgcn_mfma_f32_16x16x32_bf16(af[m], bfr[n], acc[m][n], 0, 0, 0);
  }

  const int cr = (lane >> 4) * 4;
  const int cc = lane & 15;
#pragma unroll
  for (int m = 0; m < 4; ++m) {
    const long r0 = m0 + wr * 64 + m * 16 + cr;
    const float s0 = srow[r0], s1 = srow[r0 + 1], s2 = srow[r0 + 2], s3 = srow[r0 + 3];
#pragma unroll
    for (int n = 0; n < 4; ++n) {
      const long col = n0 + wc * 64 + n * 16 + cc;
      const float wsC = wscale[col];
      const float bC = bias[col];
      float* o = C + r0 * N + col;
      o[0]          = acc[m][n][0] * (s0 * wsC) + bC;
      o[N]          = acc[m][n][1] * (s1 * wsC) + bC;
      o[2L * N]     = acc[m][n][2] * (s2 * wsC) + bC;
      o[3L * N]     = acc[m][n][3] * (s3 * wsC) + bC;
    }
  }
}

// ---------------------------------------------------------------------------
// fp32 -> bf16 convert (vectorized)
// ---------------------------------------------------------------------------
__global__ __launch_bounds__(256) void cvt_bf16(const float* __restrict__ in,
                                                __hip_bfloat16* __restrict__ out, int n4)
{
  const int i = blockIdx.x * 256 + threadIdx.x;
  if (i >= n4) return;
  f32x4 v = ((const f32x4*)in)[i];
  __hip_bfloat16 o[4];
#pragma unroll
  for (int j = 0; j < 4; ++j) o[j] = __float2bfloat16(v[j]);
  *(ushort4*)(out + i * 4L) = *(ushort4*)o;
}

// fp32 -> (hi, lo) bf16 split: hi = bf16(v), lo = bf16(v - hi)
__global__ __launch_bounds__(256) void cvt_split(const float* __restrict__ in,
                                                 __hip_bfloat16* __restrict__ hi,
                                                 __hip_bfloat16* __restrict__ lo, int n4)
{
  const int i = blockIdx.x * 256 + threadIdx.x;
  if (i >= n4) return;
  f32x4 v = ((const f32x4*)in)[i];
  __hip_bfloat16 oh[4], ol[4];
#pragma unroll
  for (int j = 0; j < 4; ++j) {
    oh[j] = __float2bfloat16(v[j]);
    ol[j] = __float2bfloat16(v[j] - __bfloat162float(oh[j]));
  }
  *(ushort4*)(hi + i * 4L) = *(ushort4*)oh;
  *(ushort4*)(lo + i * 4L) = *(ushort4*)ol;
}

// R[i][j] fp32 -> Rt[j][i] split into hi/lo bf16 (tiled transpose)
__global__ __launch_bounds__(256) void transpose_split(const float* __restrict__ in,
                                                       __hip_bfloat16* __restrict__ hi,
                                                       __hip_bfloat16* __restrict__ lo, int N)
{
  __shared__ float tile[32][33];
  const int nb = N >> 5;
  const int bx = blockIdx.x % nb, by = blockIdx.x / nb;
  const int tx = threadIdx.x & 31, ty = threadIdx.x >> 5;  // ty 0..7
#pragma unroll
  for (int i = 0; i < 4; ++i)
    tile[ty + i * 8][tx] = in[(long)(by * 32 + ty + i * 8) * N + bx * 32 + tx];
  __syncthreads();
#pragma unroll
  for (int i = 0; i < 4; ++i) {
    const float v = tile[tx][ty + i * 8];
    const __hip_bfloat16 h = __float2bfloat16(v);
    const long idx = (long)(bx * 32 + ty + i * 8) * N + by * 32 + tx;
    hi[idx] = h;
    lo[idx] = __float2bfloat16(v - __bfloat162float(h));
  }
}

__global__ __launch_bounds__(256) void invk(const float* __restrict__ cws,
                                            float* __restrict__ inv, int n)
{
  int i = blockIdx.x * 256 + threadIdx.x;
  if (i < n) inv[i] = 1.f / cws[i];
}

// ---------------------------------------------------------------------------
// Weight fake-quant, one block per output row o.
// wrot already has channel_wise_scale applied.  qw stores (q-8) in [-8,7].
// ---------------------------------------------------------------------------
__global__ __launch_bounds__(256) void wquant(
    const float* __restrict__ wrot,
    const float* __restrict__ cfmax, const float* __restrict__ cfmin,
    __hip_bfloat16* __restrict__ qw, float* __restrict__ wscale)
{
  const int row = blockIdx.x;
  const float* w = wrot + (long)row * DIN;
  const int t = threadIdx.x;
  f32x4 v0 = ((const f32x4*)w)[t];
  f32x4 v1 = ((const f32x4*)w)[t + 256];
  float vmin = v0[0], vmax = v0[0];
#pragma unroll
  for (int j = 1; j < 4; ++j) { vmin = fminf(vmin, v0[j]); vmax = fmaxf(vmax, v0[j]); }
#pragma unroll
  for (int j = 0; j < 4; ++j) { vmin = fminf(vmin, v1[j]); vmax = fmaxf(vmax, v1[j]); }
#pragma unroll
  for (int off = 32; off; off >>= 1) {
    vmin = fminf(vmin, __shfl_xor(vmin, off));
    vmax = fmaxf(vmax, __shfl_xor(vmax, off));
  }
  __shared__ float smin[4], smax[4];
  const int lane = t & 63, wid = t >> 6;
  if (lane == 0) { smin[wid] = vmin; smax[wid] = vmax; }
  __syncthreads();
  vmin = fminf(fminf(smin[0], smin[1]), fminf(smin[2], smin[3]));
  vmax = fmaxf(fmaxf(smax[0], smax[1]), fmaxf(smax[2], smax[3]));

  const float sgmax = 1.f / (1.f + expf(-cfmax[row]));
  const float sgmin = 1.f / (1.f + expf(-cfmin[row]));
  const float wminc = vmin * sgmin;
  const float wmaxc = vmax * sgmax;
  // min/max of clipped row (analytic: clip is monotone)
  float cmin = fminf(fmaxf(vmin, wminc), wmaxc);
  float cmax = fmaxf(fminf(vmax, wmaxc), wminc);
  float xmin = fminf(cmin, 0.f), xmax = fmaxf(cmax, 0.f);
  const float xm = fmaxf(fabsf(xmin), xmax);
  xmin = (xmin < 0.f) ? -xm : xmin;
  xmax = xm;
  if ((xmin == 0.f) && (xmax == 0.f)) { xmin = -1.f; xmax = 1.f; }
  const float scale = (xmax - xmin) / 15.f;
  if (t == 0) wscale[row] = scale;

  __hip_bfloat16* qr = qw + (long)row * DIN;
#pragma unroll
  for (int j = 0; j < 4; ++j) {
    float wc = fminf(fmaxf(v0[j], wminc), wmaxc);
    float q = rintf(wc / scale) + 8.f;
    q = fminf(fmaxf(q, 0.f), 15.f);
    qr[t * 4 + j] = __float2bfloat16(q - 8.f);
  }
#pragma unroll
  for (int j = 0; j < 4; ++j) {
    float wc = fminf(fmaxf(v1[j], wminc), wmaxc);
    float q = rintf(wc / scale) + 8.f;
    q = fminf(fmaxf(q, 0.f), 15.f);
    qr[1024 + t * 4 + j] = __float2bfloat16(q - 8.f);
  }
}

// ---------------------------------------------------------------------------
// Activation fake-quant, one block per token (f32 input). qh = q in [-128,127].
// ---------------------------------------------------------------------------
__global__ __launch_bounds__(256) void hquant(
    const float* __restrict__ h,
    __hip_bfloat16* __restrict__ qh,
    float* __restrict__ srow)
{
  const long row = blockIdx.x;
  const float* hr = h + row * DIN;
  const int t = threadIdx.x;
  f32x4 v0 = ((const f32x4*)hr)[t];
  f32x4 v1 = ((const f32x4*)hr)[t + 256];
  float amax = 0.f;
#pragma unroll
  for (int j = 0; j < 4; ++j) amax = fmaxf(amax, fmaxf(fabsf(v0[j]), fabsf(v1[j])));
#pragma unroll
  for (int off = 32; off; off >>= 1) amax = fmaxf(amax, __shfl_xor(amax, off));
  __shared__ float sm[4];
  const int lane = t & 63, wid = t >> 6;
  if (lane == 0) sm[wid] = amax;
  __syncthreads();
  amax = fmaxf(fmaxf(sm[0], sm[1]), fmaxf(sm[2], sm[3]));
  const float s = fmaxf(amax / 127.f, 1e-8f);
  if (t == 0) srow[row] = s;
  const float is = 1.f / s;

  __hip_bfloat16* qr = qh + row * DIN;
  __hip_bfloat16 o0[4], o1[4];
#pragma unroll
  for (int j = 0; j < 4; ++j) {
    float q = rintf(v0[j] * is);
    o0[j] = __float2bfloat16(fminf(fmaxf(q, -128.f), 127.f));
    q = rintf(v1[j] * is);
    o1[j] = __float2bfloat16(fminf(fmaxf(q, -128.f), 127.f));
  }
  *(ushort4*)(qr + t * 4) = *(ushort4*)o0;
  *(ushort4*)(qr + 1024 + t * 4) = *(ushort4*)o1;
}

// ---------------------------------------------------------------------------
extern "C" void kernel_launch(void* const* d_in, const int* in_sizes, int n_in,
                              void* d_out, int out_size, void* d_ws, size_t ws_size,
                              hipStream_t stream)
{
  const float* X     = (const float*)d_in[0];  // [4,4096,2048]
  const float* W     = (const float*)d_in[1];  // [2048,2048]
  const float* bias  = (const float*)d_in[2];  // [2048]
  const float* R     = (const float*)d_in[3];  // [2048,2048]
  const float* cws   = (const float*)d_in[4];  // [1,2048]
  const float* cfmax = (const float*)d_in[5];  // [2048,1]
  const float* cfmin = (const float*)d_in[6];  // [2048,1]
  float* out = (float*)d_out;

  // d_out (134 MB) doubles as scratch for intermediates that die before the
  // final GEMM:
  //   wrot f32 (16 MB) @ +0          live GEMM1 -> wquant
  //   Wlo  bf16 (8 MB) @ +16MB       live cvt  -> GEMM1
  //   Rtlo bf16 (8 MB) @ +24MB       live cvt  -> GEMM1
  //   h    f32 (134 MB) @ +0         live GEMM2 -> hquant (overwrites all)
  float*          wrot = (float*)d_out;
  __hip_bfloat16* Wlo  = (__hip_bfloat16*)((char*)d_out + (size_t)DOUT * DIN * 4);
  __hip_bfloat16* Rtlo = (__hip_bfloat16*)((char*)d_out + (size_t)DOUT * DIN * 4 + (size_t)DOUT * DIN * 2);
  float*          h    = (float*)d_out;

  char* ws = (char*)d_ws;
  size_t off = 0;
  auto alloc = [&](size_t bytes) -> void* {
    void* p = ws + off;
    off += (bytes + 255) & ~(size_t)255;
    return p;
  };
  __hip_bfloat16* Xb   = (__hip_bfloat16*)alloc((size_t)NTOK * DIN * 2);  // later reused as qh
  __hip_bfloat16* Rthi = (__hip_bfloat16*)alloc((size_t)DIN * DIN * 2);
  __hip_bfloat16* Whi  = (__hip_bfloat16*)alloc((size_t)DOUT * DIN * 2);  // later reused as qw
  float*          wsc  = (float*)alloc(DOUT * 4);
  float*          srow = (float*)alloc(NTOK * 4);
  float*          icws = (float*)alloc(DIN * 4);

  // 1. converts
  cvt_bf16<<<(NTOK * DIN / 4 + 255) / 256, 256, 0, stream>>>(X, Xb, NTOK * DIN / 4);
  cvt_split<<<(DOUT * DIN / 4 + 255) / 256, 256, 0, stream>>>(W, Whi, Wlo, DOUT * DIN / 4);
  transpose_split<<<(DIN / 32) * (DIN / 32), 256, 0, stream>>>(R, Rthi, Rtlo, DIN);
  invk<<<(DIN + 255) / 256, 256, 0, stream>>>(cws, icws, DIN);

  // 2. w_rot = W @ R (split precision), * cws  -> fp32 (into d_out scratch)
  gemm_wsplit<<<(DOUT / 128) * (DIN / 64), 256, 0, stream>>>(
      Whi, Wlo, Rthi, Rtlo, wrot, cws, DOUT, DIN, DIN);

  // 3. weight fake-quant -> qw (in Whi region), wscale
  wquant<<<DOUT, 256, 0, stream>>>(wrot, cfmax, cfmin, Whi, wsc);

  // 4. h = X @ R, * (1/cws) -> f32 (into d_out scratch; wrot/Wlo/Rtlo now dead)
  gemm_bt<float><<<(NTOK / 128) * (DIN / 128), 256, 0, stream>>>(
      Xb, Rthi, h, icws, NTOK, DIN, DIN);

  // 5. act fake-quant -> qh (in Xb region), srow
  hquant<<<NTOK, 256, 0, stream>>>(h, Xb, srow);

  // 6. out = qh @ qw^T * (srow*wscale) + bias
  gemm_out<<<(NTOK / 128) * (DOUT / 128), 256, 0, stream>>>(
      Xb, Whi, out, srow, wsc, bias, NTOK, DOUT, DIN);
}

// Round 4
// 649.486 us; speedup vs baseline: 1.1348x; 1.1348x over previous
//
#include <hip/hip_runtime.h>
#include <hip/hip_bf16.h>

#define DIN 2048
#define DOUT 2048
#define NTOK 16384   // B*S = 4*4096

typedef __bf16 bf16x8 __attribute__((ext_vector_type(8)));
typedef float f32x4 __attribute__((ext_vector_type(4)));
typedef int   i32x4 __attribute__((ext_vector_type(4)));
typedef char  i8x4  __attribute__((ext_vector_type(4)));

__device__ __forceinline__ void load_lds16(const void* g, void* l) {
  __builtin_amdgcn_global_load_lds((const __attribute__((address_space(1))) void*)g,
                                   (__attribute__((address_space(3))) void*)l,
                                   16, 0, 0);
}

__device__ __forceinline__ void store1(float* p, float v) { *p = v; }
__device__ __forceinline__ void store1(__hip_bfloat16* p, float v) { *p = __float2bfloat16(v); }

// ---------------------------------------------------------------------------
// C[m][n] = (sum_k A[m][k]*B[n][k]) * colf[n]    (B^T GEMM, bf16 in, fp32 acc)
// m97 structure: 128x128 tile, BK=32, 4 waves each 64x64 (4x4 frags of 16x16)
// ---------------------------------------------------------------------------
template <typename OutT>
__global__ __launch_bounds__(256) void gemm_bt(
    const __hip_bfloat16* __restrict__ A,
    const __hip_bfloat16* __restrict__ B,
    OutT* __restrict__ C,
    const float* __restrict__ colf,
    int M, int N, int K)
{
  constexpr int BK = 32;
  __shared__ __hip_bfloat16 lA[128 * BK];
  __shared__ __hip_bfloat16 lB[128 * BK];
  const int t = threadIdx.x;
  const int lane = t & 63;
  const int wid = t >> 6;
  const int wr = wid >> 1, wc = wid & 1;
  const int nbn = N / 128;
  const long m0 = (long)(blockIdx.x / nbn) * 128;
  const long n0 = (long)(blockIdx.x % nbn) * 128;

  const int offB = t * 16;            // byte offset in 8192-byte tile
  const int row0 = offB >> 6;         // 64 bytes per row (BK*2)
  const int cole = (offB & 63) >> 1;  // element offset within row

  const __hip_bfloat16* gA0 = A + (m0 + row0) * (long)K + cole;
  const __hip_bfloat16* gA1 = gA0 + 64L * K;
  const __hip_bfloat16* gB0 = B + (n0 + row0) * (long)K + cole;
  const __hip_bfloat16* gB1 = gB0 + 64L * K;
  __hip_bfloat16* lAp = lA + t * 8;
  __hip_bfloat16* lBp = lB + t * 8;

  f32x4 acc[4][4] = {};

  const int kr = (lane >> 4) * 8;
  const int rA = wr * 64 + (lane & 15);
  const int rB = wc * 64 + (lane & 15);

  for (int k0 = 0; k0 < K; k0 += BK) {
    __syncthreads();
    load_lds16(gA0 + k0, lAp);
    load_lds16(gA1 + k0, lAp + 2048);
    load_lds16(gB0 + k0, lBp);
    load_lds16(gB1 + k0, lBp + 2048);
    __syncthreads();
    bf16x8 af[4], bfr[4];
#pragma unroll
    for (int m = 0; m < 4; ++m)
      af[m] = *(const bf16x8*)(lA + (rA + m * 16) * BK + kr);
#pragma unroll
    for (int n = 0; n < 4; ++n)
      bfr[n] = *(const bf16x8*)(lB + (rB + n * 16) * BK + kr);
#pragma unroll
    for (int m = 0; m < 4; ++m)
#pragma unroll
      for (int n = 0; n < 4; ++n)
        acc[m][n] = __builtin_amdgcn_mfma_f32_16x16x32_bf16(af[m], bfr[n], acc[m][n], 0, 0, 0);
  }

  // C/D layout: col = lane&15, row = (lane>>4)*4 + e
  const int cr = (lane >> 4) * 4;
  const int cc = lane & 15;
#pragma unroll
  for (int m = 0; m < 4; ++m) {
    const long r0 = m0 + wr * 64 + m * 16 + cr;
#pragma unroll
    for (int n = 0; n < 4; ++n) {
      const long col = n0 + wc * 64 + n * 16 + cc;
      const float f = colf[col];
#pragma unroll
      for (int e = 0; e < 4; ++e)
        store1(&C[(r0 + e) * N + col], acc[m][n][e] * f);
    }
  }
}

// ---------------------------------------------------------------------------
// Split-precision GEMM for w_rot = W @ R (both operands hi+lo bf16):
//   acc += Ahi*Bhi + Ahi*Blo + Alo*Bhi   (lo*lo term ~2^-18, dropped)
// ---------------------------------------------------------------------------
__global__ __launch_bounds__(256) void gemm_wsplit(
    const __hip_bfloat16* __restrict__ Ahi, const __hip_bfloat16* __restrict__ Alo,
    const __hip_bfloat16* __restrict__ Bhi, const __hip_bfloat16* __restrict__ Blo,
    float* __restrict__ C,
    const float* __restrict__ colf,
    int M, int N, int K)
{
  constexpr int BK = 32;
  __shared__ __hip_bfloat16 lAhi[128 * BK];
  __shared__ __hip_bfloat16 lAlo[128 * BK];
  __shared__ __hip_bfloat16 lBhi[64 * BK];
  __shared__ __hip_bfloat16 lBlo[64 * BK];
  const int t = threadIdx.x;
  const int lane = t & 63;
  const int wid = t >> 6;
  const int wr = wid >> 1, wc = wid & 1;
  const int nbn = N / 64;
  const long m0 = (long)(blockIdx.x / nbn) * 128;
  const long n0 = (long)(blockIdx.x % nbn) * 64;

  const int offB = t * 16;
  const int row0 = offB >> 6;         // < 64
  const int cole = (offB & 63) >> 1;

  const long aoff = (m0 + row0) * (long)K + cole;
  const long boff = (n0 + row0) * (long)K + cole;
  __hip_bfloat16* lAp = lAhi + t * 8;
  __hip_bfloat16* lBp = lBhi + t * 8;

  f32x4 acc[4][2] = {};

  const int kr = (lane >> 4) * 8;
  const int rA = wr * 64 + (lane & 15);
  const int rB = wc * 32 + (lane & 15);

  for (int k0 = 0; k0 < K; k0 += BK) {
    __syncthreads();
    load_lds16(Ahi + aoff + k0, lAp);
    load_lds16(Ahi + aoff + 64L * K + k0, lAp + 2048);
    load_lds16(Alo + aoff + k0, lAlo + t * 8);
    load_lds16(Alo + aoff + 64L * K + k0, lAlo + t * 8 + 2048);
    load_lds16(Bhi + boff + k0, lBp);
    load_lds16(Blo + boff + k0, lBlo + t * 8);
    __syncthreads();
    bf16x8 ah[4], al[4], bh[2], bl[2];
#pragma unroll
    for (int m = 0; m < 4; ++m) {
      ah[m] = *(const bf16x8*)(lAhi + (rA + m * 16) * BK + kr);
      al[m] = *(const bf16x8*)(lAlo + (rA + m * 16) * BK + kr);
    }
#pragma unroll
    for (int n = 0; n < 2; ++n) {
      bh[n] = *(const bf16x8*)(lBhi + (rB + n * 16) * BK + kr);
      bl[n] = *(const bf16x8*)(lBlo + (rB + n * 16) * BK + kr);
    }
#pragma unroll
    for (int m = 0; m < 4; ++m)
#pragma unroll
      for (int n = 0; n < 2; ++n) {
        acc[m][n] = __builtin_amdgcn_mfma_f32_16x16x32_bf16(ah[m], bh[n], acc[m][n], 0, 0, 0);
        acc[m][n] = __builtin_amdgcn_mfma_f32_16x16x32_bf16(ah[m], bl[n], acc[m][n], 0, 0, 0);
        acc[m][n] = __builtin_amdgcn_mfma_f32_16x16x32_bf16(al[m], bh[n], acc[m][n], 0, 0, 0);
      }
  }

  const int cr = (lane >> 4) * 4;
  const int cc = lane & 15;
#pragma unroll
  for (int m = 0; m < 4; ++m) {
    const long r0 = m0 + wr * 64 + m * 16 + cr;
#pragma unroll
    for (int n = 0; n < 2; ++n) {
      const long col = n0 + wc * 32 + n * 16 + cc;
      const float f = colf[col];
#pragma unroll
      for (int e = 0; e < 4; ++e)
        C[(r0 + e) * N + col] = acc[m][n][e] * f;
    }
  }
}

// ---------------------------------------------------------------------------
// Final GEMM in i8: out[t][o] = (sum_k qh[t][k]*qwm8[o][k]) * srow[t]*wscale[o] + bias[o]
// qh in [-128,127], qwm8 = q-8 in [-8,7]; i32 accumulate -> exact.
// mfma_i32_16x16x64_i8: K=64/instr, 2x bf16 rate, half the staging bytes.
// Tile 128x128, BK=64 elems (64 B/row -> same byte geometry as bf16 BK=32).
// ---------------------------------------------------------------------------
__global__ __launch_bounds__(256) void gemm_out_i8(
    const char* __restrict__ A,
    const char* __restrict__ B,
    float* __restrict__ C,
    const float* __restrict__ srow,
    const float* __restrict__ wscale,
    const float* __restrict__ bias,
    int M, int N, int K)
{
  constexpr int BK = 64;  // elements == bytes
  __shared__ char lA[128 * BK];
  __shared__ char lB[128 * BK];
  const int t = threadIdx.x;
  const int lane = t & 63;
  const int wid = t >> 6;
  const int wr = wid >> 1, wc = wid & 1;
  const int nbn = N / 128;
  const long m0 = (long)(blockIdx.x / nbn) * 128;
  const long n0 = (long)(blockIdx.x % nbn) * 128;

  const int offB = t * 16;            // byte offset; 64 B per row
  const int row0 = offB >> 6;         // 0..63
  const int colB = offB & 63;         // byte (=elem) within row

  const char* gA0 = A + (m0 + row0) * (long)K + colB;
  const char* gA1 = gA0 + 64L * K;
  const char* gB0 = B + (n0 + row0) * (long)K + colB;
  const char* gB1 = gB0 + 64L * K;
  char* lAp = lA + t * 16;            // covers 4096B = rows 0..63
  char* lBp = lB + t * 16;

  i32x4 acc[4][4] = {};

  const int kr16 = (lane >> 4) * 16;    // byte offset of lane's k-chunk
  const int rA = wr * 64 + (lane & 15);
  const int rB = wc * 64 + (lane & 15);

  for (int k0 = 0; k0 < K; k0 += BK) {
    __syncthreads();
    load_lds16(gA0 + k0, lAp);
    load_lds16(gA1 + k0, lAp + 4096);
    load_lds16(gB0 + k0, lBp);
    load_lds16(gB1 + k0, lBp + 4096);
    __syncthreads();
    i32x4 af[4], bfr[4];
#pragma unroll
    for (int m = 0; m < 4; ++m)
      af[m] = *(const i32x4*)(lA + (rA + m * 16) * BK + kr16);
#pragma unroll
    for (int n = 0; n < 4; ++n)
      bfr[n] = *(const i32x4*)(lB + (rB + n * 16) * BK + kr16);
#pragma unroll
    for (int m = 0; m < 4; ++m)
#pragma unroll
      for (int n = 0; n < 4; ++n)
        acc[m][n] = __builtin_amdgcn_mfma_i32_16x16x64_i8(af[m], bfr[n], acc[m][n], 0, 0, 0);
  }

  const int cr = (lane >> 4) * 4;
  const int cc = lane & 15;
#pragma unroll
  for (int m = 0; m < 4; ++m) {
    const long r0 = m0 + wr * 64 + m * 16 + cr;
    const float s0 = srow[r0], s1 = srow[r0 + 1], s2 = srow[r0 + 2], s3 = srow[r0 + 3];
#pragma unroll
    for (int n = 0; n < 4; ++n) {
      const long col = n0 + wc * 64 + n * 16 + cc;
      const float wsC = wscale[col];
      const float bC = bias[col];
      float* o = C + r0 * N + col;
      o[0]      = (float)acc[m][n][0] * (s0 * wsC) + bC;
      o[N]      = (float)acc[m][n][1] * (s1 * wsC) + bC;
      o[2L * N] = (float)acc[m][n][2] * (s2 * wsC) + bC;
      o[3L * N] = (float)acc[m][n][3] * (s3 * wsC) + bC;
    }
  }
}

// ---------------------------------------------------------------------------
// fp32 -> bf16 convert (vectorized)
// ---------------------------------------------------------------------------
__global__ __launch_bounds__(256) void cvt_bf16(const float* __restrict__ in,
                                                __hip_bfloat16* __restrict__ out, int n4)
{
  const int i = blockIdx.x * 256 + threadIdx.x;
  if (i >= n4) return;
  f32x4 v = ((const f32x4*)in)[i];
  __hip_bfloat16 o[4];
#pragma unroll
  for (int j = 0; j < 4; ++j) o[j] = __float2bfloat16(v[j]);
  *(ushort4*)(out + i * 4L) = *(ushort4*)o;
}

// fp32 -> (hi, lo) bf16 split: hi = bf16(v), lo = bf16(v - hi)
__global__ __launch_bounds__(256) void cvt_split(const float* __restrict__ in,
                                                 __hip_bfloat16* __restrict__ hi,
                                                 __hip_bfloat16* __restrict__ lo, int n4)
{
  const int i = blockIdx.x * 256 + threadIdx.x;
  if (i >= n4) return;
  f32x4 v = ((const f32x4*)in)[i];
  __hip_bfloat16 oh[4], ol[4];
#pragma unroll
  for (int j = 0; j < 4; ++j) {
    oh[j] = __float2bfloat16(v[j]);
    ol[j] = __float2bfloat16(v[j] - __bfloat162float(oh[j]));
  }
  *(ushort4*)(hi + i * 4L) = *(ushort4*)oh;
  *(ushort4*)(lo + i * 4L) = *(ushort4*)ol;
}

// R[i][j] fp32 -> Rt[j][i] split into hi/lo bf16 (tiled transpose)
__global__ __launch_bounds__(256) void transpose_split(const float* __restrict__ in,
                                                       __hip_bfloat16* __restrict__ hi,
                                                       __hip_bfloat16* __restrict__ lo, int N)
{
  __shared__ float tile[32][33];
  const int nb = N >> 5;
  const int bx = blockIdx.x % nb, by = blockIdx.x / nb;
  const int tx = threadIdx.x & 31, ty = threadIdx.x >> 5;  // ty 0..7
#pragma unroll
  for (int i = 0; i < 4; ++i)
    tile[ty + i * 8][tx] = in[(long)(by * 32 + ty + i * 8) * N + bx * 32 + tx];
  __syncthreads();
#pragma unroll
  for (int i = 0; i < 4; ++i) {
    const float v = tile[tx][ty + i * 8];
    const __hip_bfloat16 h = __float2bfloat16(v);
    const long idx = (long)(bx * 32 + ty + i * 8) * N + by * 32 + tx;
    hi[idx] = h;
    lo[idx] = __float2bfloat16(v - __bfloat162float(h));
  }
}

__global__ __launch_bounds__(256) void invk(const float* __restrict__ cws,
                                            float* __restrict__ inv, int n)
{
  int i = blockIdx.x * 256 + threadIdx.x;
  if (i < n) inv[i] = 1.f / cws[i];
}

// ---------------------------------------------------------------------------
// Weight fake-quant -> i8 (q-8 in [-8,7]), one block per output row.
// ---------------------------------------------------------------------------
__global__ __launch_bounds__(256) void wquant(
    const float* __restrict__ wrot,
    const float* __restrict__ cfmax, const float* __restrict__ cfmin,
    char* __restrict__ qw, float* __restrict__ wscale)
{
  const int row = blockIdx.x;
  const float* w = wrot + (long)row * DIN;
  const int t = threadIdx.x;
  f32x4 v0 = ((const f32x4*)w)[t];
  f32x4 v1 = ((const f32x4*)w)[t + 256];
  float vmin = v0[0], vmax = v0[0];
#pragma unroll
  for (int j = 1; j < 4; ++j) { vmin = fminf(vmin, v0[j]); vmax = fmaxf(vmax, v0[j]); }
#pragma unroll
  for (int j = 0; j < 4; ++j) { vmin = fminf(vmin, v1[j]); vmax = fmaxf(vmax, v1[j]); }
#pragma unroll
  for (int off = 32; off; off >>= 1) {
    vmin = fminf(vmin, __shfl_xor(vmin, off));
    vmax = fmaxf(vmax, __shfl_xor(vmax, off));
  }
  __shared__ float smin[4], smax[4];
  const int lane = t & 63, wid = t >> 6;
  if (lane == 0) { smin[wid] = vmin; smax[wid] = vmax; }
  __syncthreads();
  vmin = fminf(fminf(smin[0], smin[1]), fminf(smin[2], smin[3]));
  vmax = fmaxf(fmaxf(smax[0], smax[1]), fmaxf(smax[2], smax[3]));

  const float sgmax = 1.f / (1.f + expf(-cfmax[row]));
  const float sgmin = 1.f / (1.f + expf(-cfmin[row]));
  const float wminc = vmin * sgmin;
  const float wmaxc = vmax * sgmax;
  // min/max of clipped row (analytic: clip is monotone)
  float cmin = fminf(fmaxf(vmin, wminc), wmaxc);
  float cmax = fmaxf(fminf(vmax, wmaxc), wminc);
  float xmin = fminf(cmin, 0.f), xmax = fmaxf(cmax, 0.f);
  const float xm = fmaxf(fabsf(xmin), xmax);
  xmin = (xmin < 0.f) ? -xm : xmin;
  xmax = xm;
  if ((xmin == 0.f) && (xmax == 0.f)) { xmin = -1.f; xmax = 1.f; }
  const float scale = (xmax - xmin) / 15.f;
  if (t == 0) wscale[row] = scale;

  char* qr = qw + (long)row * DIN;
  i8x4 o0, o1;
#pragma unroll
  for (int j = 0; j < 4; ++j) {
    float wc = fminf(fmaxf(v0[j], wminc), wmaxc);
    float q = rintf(wc / scale) + 8.f;
    q = fminf(fmaxf(q, 0.f), 15.f);
    o0[j] = (char)(int)(q - 8.f);
    wc = fminf(fmaxf(v1[j], wminc), wmaxc);
    q = rintf(wc / scale) + 8.f;
    q = fminf(fmaxf(q, 0.f), 15.f);
    o1[j] = (char)(int)(q - 8.f);
  }
  *(i8x4*)(qr + t * 4) = o0;
  *(i8x4*)(qr + 1024 + t * 4) = o1;
}

// ---------------------------------------------------------------------------
// Activation fake-quant -> i8 (q in [-128,127]), one block per token (f32 in).
// ---------------------------------------------------------------------------
__global__ __launch_bounds__(256) void hquant(
    const float* __restrict__ h,
    char* __restrict__ qh,
    float* __restrict__ srow)
{
  const long row = blockIdx.x;
  const float* hr = h + row * DIN;
  const int t = threadIdx.x;
  f32x4 v0 = ((const f32x4*)hr)[t];
  f32x4 v1 = ((const f32x4*)hr)[t + 256];
  float amax = 0.f;
#pragma unroll
  for (int j = 0; j < 4; ++j) amax = fmaxf(amax, fmaxf(fabsf(v0[j]), fabsf(v1[j])));
#pragma unroll
  for (int off = 32; off; off >>= 1) amax = fmaxf(amax, __shfl_xor(amax, off));
  __shared__ float sm[4];
  const int lane = t & 63, wid = t >> 6;
  if (lane == 0) sm[wid] = amax;
  __syncthreads();
  amax = fmaxf(fmaxf(sm[0], sm[1]), fmaxf(sm[2], sm[3]));
  const float s = fmaxf(amax / 127.f, 1e-8f);
  if (t == 0) srow[row] = s;
  const float is = 1.f / s;

  char* qr = qh + row * DIN;
  i8x4 o0, o1;
#pragma unroll
  for (int j = 0; j < 4; ++j) {
    float q = fminf(fmaxf(rintf(v0[j] * is), -128.f), 127.f);
    o0[j] = (char)(int)q;
    q = fminf(fmaxf(rintf(v1[j] * is), -128.f), 127.f);
    o1[j] = (char)(int)q;
  }
  *(i8x4*)(qr + t * 4) = o0;
  *(i8x4*)(qr + 1024 + t * 4) = o1;
}

// ---------------------------------------------------------------------------
extern "C" void kernel_launch(void* const* d_in, const int* in_sizes, int n_in,
                              void* d_out, int out_size, void* d_ws, size_t ws_size,
                              hipStream_t stream)
{
  const float* X     = (const float*)d_in[0];  // [4,4096,2048]
  const float* W     = (const float*)d_in[1];  // [2048,2048]
  const float* bias  = (const float*)d_in[2];  // [2048]
  const float* R     = (const float*)d_in[3];  // [2048,2048]
  const float* cws   = (const float*)d_in[4];  // [1,2048]
  const float* cfmax = (const float*)d_in[5];  // [2048,1]
  const float* cfmin = (const float*)d_in[6];  // [2048,1]
  float* out = (float*)d_out;

  // d_out (134 MB) doubles as scratch for intermediates that die before the
  // final GEMM:
  //   wrot f32 (16 MB) @ +0          live GEMM1 -> wquant
  //   Wlo  bf16 (8 MB) @ +16MB       live cvt  -> GEMM1
  //   Rtlo bf16 (8 MB) @ +24MB       live cvt  -> GEMM1
  //   h    f32 (134 MB) @ +0         live GEMM2 -> hquant (overwrites all)
  float*          wrot = (float*)d_out;
  __hip_bfloat16* Wlo  = (__hip_bfloat16*)((char*)d_out + (size_t)DOUT * DIN * 4);
  __hip_bfloat16* Rtlo = (__hip_bfloat16*)((char*)d_out + (size_t)DOUT * DIN * 4 + (size_t)DOUT * DIN * 2);
  float*          h    = (float*)d_out;

  char* ws = (char*)d_ws;
  size_t off = 0;
  auto alloc = [&](size_t bytes) -> void* {
    void* p = ws + off;
    off += (bytes + 255) & ~(size_t)255;
    return p;
  };
  __hip_bfloat16* Xb   = (__hip_bfloat16*)alloc((size_t)NTOK * DIN * 2);  // bf16 X
  __hip_bfloat16* Rthi = (__hip_bfloat16*)alloc((size_t)DIN * DIN * 2);
  __hip_bfloat16* Whi  = (__hip_bfloat16*)alloc((size_t)DOUT * DIN * 2);
  char*           qh   = (char*)alloc((size_t)NTOK * DIN);                // i8 activations
  char*           qw   = (char*)alloc((size_t)DOUT * DIN);                // i8 weights (q-8)
  float*          wsc  = (float*)alloc(DOUT * 4);
  float*          srow = (float*)alloc(NTOK * 4);
  float*          icws = (float*)alloc(DIN * 4);

  // 1. converts
  cvt_bf16<<<(NTOK * DIN / 4 + 255) / 256, 256, 0, stream>>>(X, Xb, NTOK * DIN / 4);
  cvt_split<<<(DOUT * DIN / 4 + 255) / 256, 256, 0, stream>>>(W, Whi, Wlo, DOUT * DIN / 4);
  transpose_split<<<(DIN / 32) * (DIN / 32), 256, 0, stream>>>(R, Rthi, Rtlo, DIN);
  invk<<<(DIN + 255) / 256, 256, 0, stream>>>(cws, icws, DIN);

  // 2. w_rot = W @ R (split precision), * cws  -> fp32 (into d_out scratch)
  gemm_wsplit<<<(DOUT / 128) * (DIN / 64), 256, 0, stream>>>(
      Whi, Wlo, Rthi, Rtlo, wrot, cws, DOUT, DIN, DIN);

  // 3. weight fake-quant -> qw (i8), wscale
  wquant<<<DOUT, 256, 0, stream>>>(wrot, cfmax, cfmin, qw, wsc);

  // 4. h = X @ R, * (1/cws) -> f32 (into d_out scratch; wrot/Wlo/Rtlo now dead)
  gemm_bt<float><<<(NTOK / 128) * (DIN / 128), 256, 0, stream>>>(
      Xb, Rthi, h, icws, NTOK, DIN, DIN);

  // 5. act fake-quant -> qh (i8), srow
  hquant<<<NTOK, 256, 0, stream>>>(h, qh, srow);

  // 6. out = qh @ qw^T * (srow*wscale) + bias   (i8 MFMA, exact)
  gemm_out_i8<<<(NTOK / 128) * (DOUT / 128), 256, 0, stream>>>(
      qh, qw, out, srow, wsc, bias, NTOK, DOUT, DIN);
}

// Round 5
// 621.307 us; speedup vs baseline: 1.1863x; 1.0454x over previous
//
#include <hip/hip_runtime.h>
#include <hip/hip_bf16.h>

#define DIN 2048
#define DOUT 2048
#define NTOK 16384   // B*S = 4*4096

typedef __bf16 bf16x8 __attribute__((ext_vector_type(8)));
typedef float f32x4 __attribute__((ext_vector_type(4)));
typedef int   i32x4 __attribute__((ext_vector_type(4)));
typedef char  i8x4  __attribute__((ext_vector_type(4)));

__device__ __forceinline__ void load_lds16(const void* g, void* l) {
  __builtin_amdgcn_global_load_lds((const __attribute__((address_space(1))) void*)g,
                                   (__attribute__((address_space(3))) void*)l,
                                   16, 0, 0);
}

__device__ __forceinline__ void store1(float* p, float v) { *p = v; }
__device__ __forceinline__ void store1(__hip_bfloat16* p, float v) { *p = __float2bfloat16(v); }

// XCD-aware bijective block swizzle (nwg % 8 == 0): XCD x gets tiles
// [x*nwg/8, (x+1)*nwg/8) -> consecutive tiles share one XCD's L2.
__device__ __forceinline__ int xcd_swz(int bid, int nwg) {
  const int cpx = nwg >> 3;
  return (bid & 7) * cpx + (bid >> 3);
}

// ---------------------------------------------------------------------------
// C[m][n] = (sum_k A[m][k]*B[n][k]) * colf[n]    (B^T GEMM, bf16 in, fp32 acc)
// m97 structure: 128x128 tile, BK=32, 4 waves each 64x64 (4x4 frags of 16x16)
// ---------------------------------------------------------------------------
template <typename OutT>
__global__ __launch_bounds__(256) void gemm_bt(
    const __hip_bfloat16* __restrict__ A,
    const __hip_bfloat16* __restrict__ B,
    OutT* __restrict__ C,
    const float* __restrict__ colf,
    int M, int N, int K)
{
  constexpr int BK = 32;
  __shared__ __hip_bfloat16 lA[128 * BK];
  __shared__ __hip_bfloat16 lB[128 * BK];
  const int t = threadIdx.x;
  const int lane = t & 63;
  const int wid = t >> 6;
  const int wr = wid >> 1, wc = wid & 1;
  const int nbn = N / 128;
  const int bid = xcd_swz(blockIdx.x, gridDim.x);
  const long m0 = (long)(bid / nbn) * 128;
  const long n0 = (long)(bid % nbn) * 128;

  const int offB = t * 16;            // byte offset in 8192-byte tile
  const int row0 = offB >> 6;         // 64 bytes per row (BK*2)
  const int cole = (offB & 63) >> 1;  // element offset within row

  const __hip_bfloat16* gA0 = A + (m0 + row0) * (long)K + cole;
  const __hip_bfloat16* gA1 = gA0 + 64L * K;
  const __hip_bfloat16* gB0 = B + (n0 + row0) * (long)K + cole;
  const __hip_bfloat16* gB1 = gB0 + 64L * K;
  __hip_bfloat16* lAp = lA + t * 8;
  __hip_bfloat16* lBp = lB + t * 8;

  f32x4 acc[4][4] = {};

  const int kr = (lane >> 4) * 8;
  const int rA = wr * 64 + (lane & 15);
  const int rB = wc * 64 + (lane & 15);

  for (int k0 = 0; k0 < K; k0 += BK) {
    __syncthreads();
    load_lds16(gA0 + k0, lAp);
    load_lds16(gA1 + k0, lAp + 2048);
    load_lds16(gB0 + k0, lBp);
    load_lds16(gB1 + k0, lBp + 2048);
    __syncthreads();
    bf16x8 af[4], bfr[4];
#pragma unroll
    for (int m = 0; m < 4; ++m)
      af[m] = *(const bf16x8*)(lA + (rA + m * 16) * BK + kr);
#pragma unroll
    for (int n = 0; n < 4; ++n)
      bfr[n] = *(const bf16x8*)(lB + (rB + n * 16) * BK + kr);
#pragma unroll
    for (int m = 0; m < 4; ++m)
#pragma unroll
      for (int n = 0; n < 4; ++n)
        acc[m][n] = __builtin_amdgcn_mfma_f32_16x16x32_bf16(af[m], bfr[n], acc[m][n], 0, 0, 0);
  }

  // C/D layout: col = lane&15, row = (lane>>4)*4 + e
  const int cr = (lane >> 4) * 4;
  const int cc = lane & 15;
#pragma unroll
  for (int m = 0; m < 4; ++m) {
    const long r0 = m0 + wr * 64 + m * 16 + cr;
#pragma unroll
    for (int n = 0; n < 4; ++n) {
      const long col = n0 + wc * 64 + n * 16 + cc;
      const float f = colf[col];
#pragma unroll
      for (int e = 0; e < 4; ++e)
        store1(&C[(r0 + e) * N + col], acc[m][n][e] * f);
    }
  }
}

// ---------------------------------------------------------------------------
// w_rot = (Whi + Wlo) @ S * colf  -- S is the exact ±1 sign matrix (B^T form),
// so 2 MFMAs/frag give w_rot to ~2^-17 relative (bf16 hi+lo of W, exact B).
// Tile 128x64, BK=32, 4 waves (2x2), wave tile 64x32 = 4x2 frags.
// ---------------------------------------------------------------------------
__global__ __launch_bounds__(256) void gemm_wsplit2(
    const __hip_bfloat16* __restrict__ Ahi, const __hip_bfloat16* __restrict__ Alo,
    const __hip_bfloat16* __restrict__ Bs,
    float* __restrict__ C,
    const float* __restrict__ colf,
    int M, int N, int K)
{
  constexpr int BK = 32;
  __shared__ __hip_bfloat16 lAhi[128 * BK];
  __shared__ __hip_bfloat16 lAlo[128 * BK];
  __shared__ __hip_bfloat16 lB[64 * BK];
  const int t = threadIdx.x;
  const int lane = t & 63;
  const int wid = t >> 6;
  const int wr = wid >> 1, wc = wid & 1;
  const int nbn = N / 64;
  const int bid = xcd_swz(blockIdx.x, gridDim.x);
  const long m0 = (long)(bid / nbn) * 128;
  const long n0 = (long)(bid % nbn) * 64;

  const int offB = t * 16;
  const int row0 = offB >> 6;         // < 64
  const int cole = (offB & 63) >> 1;

  const long aoff = (m0 + row0) * (long)K + cole;
  const long boff = (n0 + row0) * (long)K + cole;

  f32x4 acc[4][2] = {};

  const int kr = (lane >> 4) * 8;
  const int rA = wr * 64 + (lane & 15);
  const int rB = wc * 32 + (lane & 15);

  for (int k0 = 0; k0 < K; k0 += BK) {
    __syncthreads();
    load_lds16(Ahi + aoff + k0, lAhi + t * 8);
    load_lds16(Ahi + aoff + 64L * K + k0, lAhi + t * 8 + 2048);
    load_lds16(Alo + aoff + k0, lAlo + t * 8);
    load_lds16(Alo + aoff + 64L * K + k0, lAlo + t * 8 + 2048);
    load_lds16(Bs + boff + k0, lB + t * 8);
    __syncthreads();
    bf16x8 ah[4], al[4], bs[2];
#pragma unroll
    for (int m = 0; m < 4; ++m) {
      ah[m] = *(const bf16x8*)(lAhi + (rA + m * 16) * BK + kr);
      al[m] = *(const bf16x8*)(lAlo + (rA + m * 16) * BK + kr);
    }
#pragma unroll
    for (int n = 0; n < 2; ++n)
      bs[n] = *(const bf16x8*)(lB + (rB + n * 16) * BK + kr);
#pragma unroll
    for (int m = 0; m < 4; ++m)
#pragma unroll
      for (int n = 0; n < 2; ++n) {
        acc[m][n] = __builtin_amdgcn_mfma_f32_16x16x32_bf16(ah[m], bs[n], acc[m][n], 0, 0, 0);
        acc[m][n] = __builtin_amdgcn_mfma_f32_16x16x32_bf16(al[m], bs[n], acc[m][n], 0, 0, 0);
      }
  }

  const int cr = (lane >> 4) * 4;
  const int cc = lane & 15;
#pragma unroll
  for (int m = 0; m < 4; ++m) {
    const long r0 = m0 + wr * 64 + m * 16 + cr;
#pragma unroll
    for (int n = 0; n < 2; ++n) {
      const long col = n0 + wc * 32 + n * 16 + cc;
      const float f = colf[col];
#pragma unroll
      for (int e = 0; e < 4; ++e)
        C[(r0 + e) * N + col] = acc[m][n][e] * f;
    }
  }
}

// ---------------------------------------------------------------------------
// Final GEMM in i8: out[t][o] = (sum_k qh[t][k]*qwm8[o][k]) * srow[t]*wscale[o] + bias[o]
// qh in [-128,127], qwm8 = q-8 in [-8,7]; i32 accumulate -> exact.
// ---------------------------------------------------------------------------
__global__ __launch_bounds__(256) void gemm_out_i8(
    const char* __restrict__ A,
    const char* __restrict__ B,
    float* __restrict__ C,
    const float* __restrict__ srow,
    const float* __restrict__ wscale,
    const float* __restrict__ bias,
    int M, int N, int K)
{
  constexpr int BK = 64;  // elements == bytes
  __shared__ char lA[128 * BK];
  __shared__ char lB[128 * BK];
  const int t = threadIdx.x;
  const int lane = t & 63;
  const int wid = t >> 6;
  const int wr = wid >> 1, wc = wid & 1;
  const int nbn = N / 128;
  const int bid = xcd_swz(blockIdx.x, gridDim.x);
  const long m0 = (long)(bid / nbn) * 128;
  const long n0 = (long)(bid % nbn) * 128;

  const int offB = t * 16;            // byte offset; 64 B per row
  const int row0 = offB >> 6;         // 0..63
  const int colB = offB & 63;         // byte (=elem) within row

  const char* gA0 = A + (m0 + row0) * (long)K + colB;
  const char* gA1 = gA0 + 64L * K;
  const char* gB0 = B + (n0 + row0) * (long)K + colB;
  const char* gB1 = gB0 + 64L * K;
  char* lAp = lA + t * 16;
  char* lBp = lB + t * 16;

  i32x4 acc[4][4] = {};

  const int kr16 = (lane >> 4) * 16;
  const int rA = wr * 64 + (lane & 15);
  const int rB = wc * 64 + (lane & 15);

  for (int k0 = 0; k0 < K; k0 += BK) {
    __syncthreads();
    load_lds16(gA0 + k0, lAp);
    load_lds16(gA1 + k0, lAp + 4096);
    load_lds16(gB0 + k0, lBp);
    load_lds16(gB1 + k0, lBp + 4096);
    __syncthreads();
    i32x4 af[4], bfr[4];
#pragma unroll
    for (int m = 0; m < 4; ++m)
      af[m] = *(const i32x4*)(lA + (rA + m * 16) * BK + kr16);
#pragma unroll
    for (int n = 0; n < 4; ++n)
      bfr[n] = *(const i32x4*)(lB + (rB + n * 16) * BK + kr16);
#pragma unroll
    for (int m = 0; m < 4; ++m)
#pragma unroll
      for (int n = 0; n < 4; ++n)
        acc[m][n] = __builtin_amdgcn_mfma_i32_16x16x64_i8(af[m], bfr[n], acc[m][n], 0, 0, 0);
  }

  const int cr = (lane >> 4) * 4;
  const int cc = lane & 15;
#pragma unroll
  for (int m = 0; m < 4; ++m) {
    const long r0 = m0 + wr * 64 + m * 16 + cr;
    const float s0 = srow[r0], s1 = srow[r0 + 1], s2 = srow[r0 + 2], s3 = srow[r0 + 3];
#pragma unroll
    for (int n = 0; n < 4; ++n) {
      const long col = n0 + wc * 64 + n * 16 + cc;
      const float wsC = wscale[col];
      const float bC = bias[col];
      float* o = C + r0 * N + col;
      o[0]      = (float)acc[m][n][0] * (s0 * wsC) + bC;
      o[N]      = (float)acc[m][n][1] * (s1 * wsC) + bC;
      o[2L * N] = (float)acc[m][n][2] * (s2 * wsC) + bC;
      o[3L * N] = (float)acc[m][n][3] * (s3 * wsC) + bC;
    }
  }
}

// ---------------------------------------------------------------------------
// fp32 -> bf16 convert (vectorized)
// ---------------------------------------------------------------------------
__global__ __launch_bounds__(256) void cvt_bf16(const float* __restrict__ in,
                                                __hip_bfloat16* __restrict__ out, int n4)
{
  const int i = blockIdx.x * 256 + threadIdx.x;
  if (i >= n4) return;
  f32x4 v = ((const f32x4*)in)[i];
  __hip_bfloat16 o[4];
#pragma unroll
  for (int j = 0; j < 4; ++j) o[j] = __float2bfloat16(v[j]);
  *(ushort4*)(out + i * 4L) = *(ushort4*)o;
}

// fp32 -> (hi, lo) bf16 split: hi = bf16(v), lo = bf16(v - hi)
__global__ __launch_bounds__(256) void cvt_split(const float* __restrict__ in,
                                                 __hip_bfloat16* __restrict__ hi,
                                                 __hip_bfloat16* __restrict__ lo, int n4)
{
  const int i = blockIdx.x * 256 + threadIdx.x;
  if (i >= n4) return;
  f32x4 v = ((const f32x4*)in)[i];
  __hip_bfloat16 oh[4], ol[4];
#pragma unroll
  for (int j = 0; j < 4; ++j) {
    oh[j] = __float2bfloat16(v[j]);
    ol[j] = __float2bfloat16(v[j] - __bfloat162float(oh[j]));
  }
  *(ushort4*)(hi + i * 4L) = *(ushort4*)oh;
  *(ushort4*)(lo + i * 4L) = *(ushort4*)ol;
}

// R[i][j] fp32 -> Sb[j][i] = sign(R[i][j]) as bf16 ±1 (tiled transpose).
// R is a signed Hadamard / sqrt(n): every entry has identical magnitude r0,
// so R = r0 * S exactly (in fp32), with S the ±1 matrix extracted here.
__global__ __launch_bounds__(256) void transpose_sign(const float* __restrict__ in,
                                                      __hip_bfloat16* __restrict__ out, int N)
{
  __shared__ float tile[32][33];
  const int nb = N >> 5;
  const int bx = blockIdx.x % nb, by = blockIdx.x / nb;
  const int tx = threadIdx.x & 31, ty = threadIdx.x >> 5;  // ty 0..7
#pragma unroll
  for (int i = 0; i < 4; ++i)
    tile[ty + i * 8][tx] = in[(long)(by * 32 + ty + i * 8) * N + bx * 32 + tx];
  __syncthreads();
#pragma unroll
  for (int i = 0; i < 4; ++i) {
    const float v = tile[tx][ty + i * 8];
    // bf16(+1)=0x3F80, bf16(-1)=0xBF80
    const unsigned short s = (unsigned short)(0x3F80u | ((__float_as_uint(v) >> 16) & 0x8000u));
    *(unsigned short*)&out[(long)(bx * 32 + ty + i * 8) * N + by * 32 + tx] = s;
  }
}

// colf1[i] = cws[i]*r0 (for w_rot), colf2[i] = r0/cws[i] (for h), r0 = |R[0]|
__global__ __launch_bounds__(256) void make_colf(const float* __restrict__ cws,
                                                 const float* __restrict__ R,
                                                 float* __restrict__ colf1,
                                                 float* __restrict__ colf2, int n)
{
  const int i = blockIdx.x * 256 + threadIdx.x;
  const float r0 = fabsf(R[0]);
  if (i < n) {
    colf1[i] = cws[i] * r0;
    colf2[i] = r0 / cws[i];
  }
}

// ---------------------------------------------------------------------------
// Weight fake-quant -> i8 (q-8 in [-8,7]), one block per output row.
// ---------------------------------------------------------------------------
__global__ __launch_bounds__(256) void wquant(
    const float* __restrict__ wrot,
    const float* __restrict__ cfmax, const float* __restrict__ cfmin,
    char* __restrict__ qw, float* __restrict__ wscale)
{
  const int row = blockIdx.x;
  const float* w = wrot + (long)row * DIN;
  const int t = threadIdx.x;
  f32x4 v0 = ((const f32x4*)w)[t];
  f32x4 v1 = ((const f32x4*)w)[t + 256];
  float vmin = v0[0], vmax = v0[0];
#pragma unroll
  for (int j = 1; j < 4; ++j) { vmin = fminf(vmin, v0[j]); vmax = fmaxf(vmax, v0[j]); }
#pragma unroll
  for (int j = 0; j < 4; ++j) { vmin = fminf(vmin, v1[j]); vmax = fmaxf(vmax, v1[j]); }
#pragma unroll
  for (int off = 32; off; off >>= 1) {
    vmin = fminf(vmin, __shfl_xor(vmin, off));
    vmax = fmaxf(vmax, __shfl_xor(vmax, off));
  }
  __shared__ float smin[4], smax[4];
  const int lane = t & 63, wid = t >> 6;
  if (lane == 0) { smin[wid] = vmin; smax[wid] = vmax; }
  __syncthreads();
  vmin = fminf(fminf(smin[0], smin[1]), fminf(smin[2], smin[3]));
  vmax = fmaxf(fmaxf(smax[0], smax[1]), fmaxf(smax[2], smax[3]));

  const float sgmax = 1.f / (1.f + expf(-cfmax[row]));
  const float sgmin = 1.f / (1.f + expf(-cfmin[row]));
  const float wminc = vmin * sgmin;
  const float wmaxc = vmax * sgmax;
  // min/max of clipped row (analytic: clip is monotone)
  float cmin = fminf(fmaxf(vmin, wminc), wmaxc);
  float cmax = fmaxf(fminf(vmax, wmaxc), wminc);
  float xmin = fminf(cmin, 0.f), xmax = fmaxf(cmax, 0.f);
  const float xm = fmaxf(fabsf(xmin), xmax);
  xmin = (xmin < 0.f) ? -xm : xmin;
  xmax = xm;
  if ((xmin == 0.f) && (xmax == 0.f)) { xmin = -1.f; xmax = 1.f; }
  const float scale = (xmax - xmin) / 15.f;
  if (t == 0) wscale[row] = scale;

  char* qr = qw + (long)row * DIN;
  i8x4 o0, o1;
#pragma unroll
  for (int j = 0; j < 4; ++j) {
    float wc = fminf(fmaxf(v0[j], wminc), wmaxc);
    float q = rintf(wc / scale) + 8.f;
    q = fminf(fmaxf(q, 0.f), 15.f);
    o0[j] = (char)(int)(q - 8.f);
    wc = fminf(fmaxf(v1[j], wminc), wmaxc);
    q = rintf(wc / scale) + 8.f;
    q = fminf(fmaxf(q, 0.f), 15.f);
    o1[j] = (char)(int)(q - 8.f);
  }
  *(i8x4*)(qr + t * 4) = o0;
  *(i8x4*)(qr + 1024 + t * 4) = o1;
}

// ---------------------------------------------------------------------------
// Activation fake-quant -> i8 (q in [-128,127]), one block per token (bf16 in).
// ---------------------------------------------------------------------------
__global__ __launch_bounds__(256) void hquant(
    const __hip_bfloat16* __restrict__ h,
    char* __restrict__ qh,
    float* __restrict__ srow)
{
  const long row = blockIdx.x;
  const __hip_bfloat16* hr = h + row * DIN;
  const int t = threadIdx.x;
  bf16x8 v = *(const bf16x8*)(hr + t * 8);
  float f[8];
  float amax = 0.f;
#pragma unroll
  for (int j = 0; j < 8; ++j) { f[j] = (float)v[j]; amax = fmaxf(amax, fabsf(f[j])); }
#pragma unroll
  for (int off = 32; off; off >>= 1) amax = fmaxf(amax, __shfl_xor(amax, off));
  __shared__ float sm[4];
  const int lane = t & 63, wid = t >> 6;
  if (lane == 0) sm[wid] = amax;
  __syncthreads();
  amax = fmaxf(fmaxf(sm[0], sm[1]), fmaxf(sm[2], sm[3]));
  const float s = fmaxf(amax / 127.f, 1e-8f);
  if (t == 0) srow[row] = s;
  const float is = 1.f / s;

  char o[8];
#pragma unroll
  for (int j = 0; j < 8; ++j) {
    float q = fminf(fmaxf(rintf(f[j] * is), -128.f), 127.f);
    o[j] = (char)(int)q;
  }
  *(uint2*)(qh + row * DIN + t * 8) = *(uint2*)o;
}

// ---------------------------------------------------------------------------
extern "C" void kernel_launch(void* const* d_in, const int* in_sizes, int n_in,
                              void* d_out, int out_size, void* d_ws, size_t ws_size,
                              hipStream_t stream)
{
  const float* X     = (const float*)d_in[0];  // [4,4096,2048]
  const float* W     = (const float*)d_in[1];  // [2048,2048]
  const float* bias  = (const float*)d_in[2];  // [2048]
  const float* R     = (const float*)d_in[3];  // [2048,2048]
  const float* cws   = (const float*)d_in[4];  // [1,2048]
  const float* cfmax = (const float*)d_in[5];  // [2048,1]
  const float* cfmin = (const float*)d_in[6];  // [2048,1]
  float* out = (float*)d_out;

  // d_out (134 MB) doubles as scratch for intermediates that die before the
  // final GEMM:
  //   wrot f32 (16 MB) @ +0        live GEMM1 -> wquant
  //   Wlo  bf16 (8 MB) @ +16MB     live cvt   -> GEMM1
  //   h    bf16 (67 MB) @ +0       live GEMM2 -> hquant (overwrites all)
  float*          wrot = (float*)d_out;
  __hip_bfloat16* Wlo  = (__hip_bfloat16*)((char*)d_out + (size_t)DOUT * DIN * 4);
  __hip_bfloat16* h    = (__hip_bfloat16*)d_out;

  char* ws = (char*)d_ws;
  size_t off = 0;
  auto alloc = [&](size_t bytes) -> void* {
    void* p = ws + off;
    off += (bytes + 255) & ~(size_t)255;
    return p;
  };
  __hip_bfloat16* Xb    = (__hip_bfloat16*)alloc((size_t)NTOK * DIN * 2);  // bf16 X
  __hip_bfloat16* Sb    = (__hip_bfloat16*)alloc((size_t)DIN * DIN * 2);   // sign(R)^T, ±1
  __hip_bfloat16* Whi   = (__hip_bfloat16*)alloc((size_t)DOUT * DIN * 2);
  char*           qh    = (char*)alloc((size_t)NTOK * DIN);                // i8 activations
  char*           qw    = (char*)alloc((size_t)DOUT * DIN);                // i8 weights (q-8)
  float*          wsc   = (float*)alloc(DOUT * 4);
  float*          srow  = (float*)alloc(NTOK * 4);
  float*          colf1 = (float*)alloc(DIN * 4);
  float*          colf2 = (float*)alloc(DIN * 4);

  // 1. converts
  cvt_bf16<<<(NTOK * DIN / 4 + 255) / 256, 256, 0, stream>>>(X, Xb, NTOK * DIN / 4);
  cvt_split<<<(DOUT * DIN / 4 + 255) / 256, 256, 0, stream>>>(W, Whi, Wlo, DOUT * DIN / 4);
  transpose_sign<<<(DIN / 32) * (DIN / 32), 256, 0, stream>>>(R, Sb, DIN);
  make_colf<<<(DIN + 255) / 256, 256, 0, stream>>>(cws, R, colf1, colf2, DIN);

  // 2. w_rot = r0*(W@S) * cws -> fp32 (into d_out scratch); W split hi+lo, S exact
  gemm_wsplit2<<<(DOUT / 128) * (DIN / 64), 256, 0, stream>>>(
      Whi, Wlo, Sb, wrot, colf1, DOUT, DIN, DIN);

  // 3. weight fake-quant -> qw (i8), wscale
  wquant<<<DOUT, 256, 0, stream>>>(wrot, cfmax, cfmin, qw, wsc);

  // 4. h = r0*(X@S) / cws -> bf16 (into d_out scratch; wrot/Wlo now dead)
  gemm_bt<__hip_bfloat16><<<(NTOK / 128) * (DIN / 128), 256, 0, stream>>>(
      Xb, Sb, h, colf2, NTOK, DIN, DIN);

  // 5. act fake-quant -> qh (i8), srow
  hquant<<<NTOK, 256, 0, stream>>>(h, qh, srow);

  // 6. out = qh @ qw^T * (srow*wscale) + bias   (i8 MFMA, exact)
  gemm_out_i8<<<(NTOK / 128) * (DOUT / 128), 256, 0, stream>>>(
      qh, qw, out, srow, wsc, bias, NTOK, DOUT, DIN);
}

// Round 7
// 593.305 us; speedup vs baseline: 1.2423x; 1.0472x over previous
//
#include <hip/hip_runtime.h>
#include <hip/hip_bf16.h>

#define DIN 2048
#define DOUT 2048
#define NTOK 16384   // B*S = 4*4096

typedef __bf16 bf16x8 __attribute__((ext_vector_type(8)));
typedef float f32x4 __attribute__((ext_vector_type(4)));
typedef int   i32x4 __attribute__((ext_vector_type(4)));
typedef char  i8x4  __attribute__((ext_vector_type(4)));

__device__ __forceinline__ void load_lds16(const void* g, void* l) {
  __builtin_amdgcn_global_load_lds((const __attribute__((address_space(1))) void*)g,
                                   (__attribute__((address_space(3))) void*)l,
                                   16, 0, 0);
}

__device__ __forceinline__ void store1(float* p, float v) { *p = v; }
__device__ __forceinline__ void store1(__hip_bfloat16* p, float v) { *p = __float2bfloat16(v); }

// XCD-aware bijective block swizzle (nwg % 8 == 0)
__device__ __forceinline__ int xcd_swz(int bid, int nwg) {
  const int cpx = nwg >> 3;
  return (bid & 7) * cpx + (bid >> 3);
}

// ---------------------------------------------------------------------------
// C[m][n] = (sum_k A[m][k]*B[n][k]) * colf[n]    (B^T GEMM, bf16 in, fp32 acc)
// 128x128 tile, BK=32, 4 waves, T3-minimum double-buffer:
//   stage(t+1 -> buf^1) issued BEFORE compute(buf), one barrier per K-step.
// ---------------------------------------------------------------------------
template <typename OutT>
__global__ __launch_bounds__(256) void gemm_bt(
    const __hip_bfloat16* __restrict__ A,
    const __hip_bfloat16* __restrict__ B,
    OutT* __restrict__ C,
    const float* __restrict__ colf,
    int M, int N, int K)
{
  constexpr int BK = 32;
  __shared__ __hip_bfloat16 lA[2][128 * BK];
  __shared__ __hip_bfloat16 lB[2][128 * BK];
  const int t = threadIdx.x;
  const int lane = t & 63;
  const int wid = t >> 6;
  const int wr = wid >> 1, wc = wid & 1;
  const int nbn = N / 128;
  const int bid = xcd_swz(blockIdx.x, gridDim.x);
  const long m0 = (long)(bid / nbn) * 128;
  const long n0 = (long)(bid % nbn) * 128;

  const int offB = t * 16;            // byte offset in 8192-byte tile
  const int row0 = offB >> 6;         // 64 bytes per row (BK*2)
  const int cole = (offB & 63) >> 1;  // element offset within row

  const __hip_bfloat16* gA0 = A + (m0 + row0) * (long)K + cole;
  const __hip_bfloat16* gA1 = gA0 + 64L * K;
  const __hip_bfloat16* gB0 = B + (n0 + row0) * (long)K + cole;
  const __hip_bfloat16* gB1 = gB0 + 64L * K;

  f32x4 acc[4][4] = {};

  const int kr = (lane >> 4) * 8;
  const int rA = wr * 64 + (lane & 15);
  const int rB = wc * 64 + (lane & 15);

  // prologue: stage tile 0 into buf 0
  load_lds16(gA0, lA[0] + t * 8);
  load_lds16(gA1, lA[0] + t * 8 + 2048);
  load_lds16(gB0, lB[0] + t * 8);
  load_lds16(gB1, lB[0] + t * 8 + 2048);
  __syncthreads();   // compiler emits vmcnt(0) drain before s_barrier

  int cur = 0;
  for (int k0 = 0; k0 < K; k0 += BK) {
    // issue next-tile staging into the other buffer (in flight during MFMA)
    if (k0 + BK < K) {
      const int nxt = cur ^ 1;
      load_lds16(gA0 + k0 + BK, lA[nxt] + t * 8);
      load_lds16(gA1 + k0 + BK, lA[nxt] + t * 8 + 2048);
      load_lds16(gB0 + k0 + BK, lB[nxt] + t * 8);
      load_lds16(gB1 + k0 + BK, lB[nxt] + t * 8 + 2048);
    }
    bf16x8 af[4], bfr[4];
#pragma unroll
    for (int m = 0; m < 4; ++m)
      af[m] = *(const bf16x8*)(lA[cur] + (rA + m * 16) * BK + kr);
#pragma unroll
    for (int n = 0; n < 4; ++n)
      bfr[n] = *(const bf16x8*)(lB[cur] + (rB + n * 16) * BK + kr);
    __builtin_amdgcn_s_setprio(1);
#pragma unroll
    for (int m = 0; m < 4; ++m)
#pragma unroll
      for (int n = 0; n < 4; ++n)
        acc[m][n] = __builtin_amdgcn_mfma_f32_16x16x32_bf16(af[m], bfr[n], acc[m][n], 0, 0, 0);
    __builtin_amdgcn_s_setprio(0);
    __syncthreads();   // drains next-tile loads; protects buf reuse
    cur ^= 1;
  }

  // C/D layout: col = lane&15, row = (lane>>4)*4 + e
  const int cr = (lane >> 4) * 4;
  const int cc = lane & 15;
#pragma unroll
  for (int m = 0; m < 4; ++m) {
    const long r0 = m0 + wr * 64 + m * 16 + cr;
#pragma unroll
    for (int n = 0; n < 4; ++n) {
      const long col = n0 + wc * 64 + n * 16 + cc;
      const float f = colf[col];
#pragma unroll
      for (int e = 0; e < 4; ++e)
        store1(&C[(r0 + e) * N + col], acc[m][n][e] * f);
    }
  }
}

// ---------------------------------------------------------------------------
// w_rot = (Whi + Wlo) @ S * colf  -- S exact ±1 sign matrix (B^T form).
// Tile 128x64, BK=32, double-buffered like gemm_bt.
// ---------------------------------------------------------------------------
__global__ __launch_bounds__(256) void gemm_wsplit2(
    const __hip_bfloat16* __restrict__ Ahi, const __hip_bfloat16* __restrict__ Alo,
    const __hip_bfloat16* __restrict__ Bs,
    float* __restrict__ C,
    const float* __restrict__ colf,
    int M, int N, int K)
{
  constexpr int BK = 32;
  __shared__ __hip_bfloat16 lAhi[2][128 * BK];
  __shared__ __hip_bfloat16 lAlo[2][128 * BK];
  __shared__ __hip_bfloat16 lB[2][64 * BK];
  const int t = threadIdx.x;
  const int lane = t & 63;
  const int wid = t >> 6;
  const int wr = wid >> 1, wc = wid & 1;
  const int nbn = N / 64;
  const int bid = xcd_swz(blockIdx.x, gridDim.x);
  const long m0 = (long)(bid / nbn) * 128;
  const long n0 = (long)(bid % nbn) * 64;

  const int offB = t * 16;
  const int row0 = offB >> 6;         // < 64
  const int cole = (offB & 63) >> 1;

  const long aoff = (m0 + row0) * (long)K + cole;
  const long boff = (n0 + row0) * (long)K + cole;

  f32x4 acc[4][2] = {};

  const int kr = (lane >> 4) * 8;
  const int rA = wr * 64 + (lane & 15);
  const int rB = wc * 32 + (lane & 15);

  load_lds16(Ahi + aoff, lAhi[0] + t * 8);
  load_lds16(Ahi + aoff + 64L * K, lAhi[0] + t * 8 + 2048);
  load_lds16(Alo + aoff, lAlo[0] + t * 8);
  load_lds16(Alo + aoff + 64L * K, lAlo[0] + t * 8 + 2048);
  load_lds16(Bs + boff, lB[0] + t * 8);
  __syncthreads();

  int cur = 0;
  for (int k0 = 0; k0 < K; k0 += BK) {
    if (k0 + BK < K) {
      const int nxt = cur ^ 1;
      load_lds16(Ahi + aoff + k0 + BK, lAhi[nxt] + t * 8);
      load_lds16(Ahi + aoff + 64L * K + k0 + BK, lAhi[nxt] + t * 8 + 2048);
      load_lds16(Alo + aoff + k0 + BK, lAlo[nxt] + t * 8);
      load_lds16(Alo + aoff + 64L * K + k0 + BK, lAlo[nxt] + t * 8 + 2048);
      load_lds16(Bs + boff + k0 + BK, lB[nxt] + t * 8);
    }
    bf16x8 ah[4], al[4], bs[2];
#pragma unroll
    for (int m = 0; m < 4; ++m) {
      ah[m] = *(const bf16x8*)(lAhi[cur] + (rA + m * 16) * BK + kr);
      al[m] = *(const bf16x8*)(lAlo[cur] + (rA + m * 16) * BK + kr);
    }
#pragma unroll
    for (int n = 0; n < 2; ++n)
      bs[n] = *(const bf16x8*)(lB[cur] + (rB + n * 16) * BK + kr);
    __builtin_amdgcn_s_setprio(1);
#pragma unroll
    for (int m = 0; m < 4; ++m)
#pragma unroll
      for (int n = 0; n < 2; ++n) {
        acc[m][n] = __builtin_amdgcn_mfma_f32_16x16x32_bf16(ah[m], bs[n], acc[m][n], 0, 0, 0);
        acc[m][n] = __builtin_amdgcn_mfma_f32_16x16x32_bf16(al[m], bs[n], acc[m][n], 0, 0, 0);
      }
    __builtin_amdgcn_s_setprio(0);
    __syncthreads();
    cur ^= 1;
  }

  const int cr = (lane >> 4) * 4;
  const int cc = lane & 15;
#pragma unroll
  for (int m = 0; m < 4; ++m) {
    const long r0 = m0 + wr * 64 + m * 16 + cr;
#pragma unroll
    for (int n = 0; n < 2; ++n) {
      const long col = n0 + wc * 32 + n * 16 + cc;
      const float f = colf[col];
#pragma unroll
      for (int e = 0; e < 4; ++e)
        C[(r0 + e) * N + col] = acc[m][n][e] * f;
    }
  }
}

// ---------------------------------------------------------------------------
// Final GEMM in i8 (exact): out = (qh @ qw^T) * srow*wscale + bias
// 128x128 tile, BK=64 bytes, double-buffered.
// ---------------------------------------------------------------------------
__global__ __launch_bounds__(256) void gemm_out_i8(
    const char* __restrict__ A,
    const char* __restrict__ B,
    float* __restrict__ C,
    const float* __restrict__ srow,
    const float* __restrict__ wscale,
    const float* __restrict__ bias,
    int M, int N, int K)
{
  constexpr int BK = 64;  // elements == bytes
  __shared__ char lA[2][128 * BK];
  __shared__ char lB[2][128 * BK];
  const int t = threadIdx.x;
  const int lane = t & 63;
  const int wid = t >> 6;
  const int wr = wid >> 1, wc = wid & 1;
  const int nbn = N / 128;
  const int bid = xcd_swz(blockIdx.x, gridDim.x);
  const long m0 = (long)(bid / nbn) * 128;
  const long n0 = (long)(bid % nbn) * 128;

  const int offB = t * 16;            // byte offset; 64 B per row
  const int row0 = offB >> 6;         // 0..63
  const int colB = offB & 63;

  const char* gA0 = A + (m0 + row0) * (long)K + colB;
  const char* gA1 = gA0 + 64L * K;
  const char* gB0 = B + (n0 + row0) * (long)K + colB;
  const char* gB1 = gB0 + 64L * K;

  i32x4 acc[4][4] = {};

  const int kr16 = (lane >> 4) * 16;
  const int rA = wr * 64 + (lane & 15);
  const int rB = wc * 64 + (lane & 15);

  load_lds16(gA0, lA[0] + t * 16);
  load_lds16(gA1, lA[0] + t * 16 + 4096);
  load_lds16(gB0, lB[0] + t * 16);
  load_lds16(gB1, lB[0] + t * 16 + 4096);
  __syncthreads();

  int cur = 0;
  for (int k0 = 0; k0 < K; k0 += BK) {
    if (k0 + BK < K) {
      const int nxt = cur ^ 1;
      load_lds16(gA0 + k0 + BK, lA[nxt] + t * 16);
      load_lds16(gA1 + k0 + BK, lA[nxt] + t * 16 + 4096);
      load_lds16(gB0 + k0 + BK, lB[nxt] + t * 16);
      load_lds16(gB1 + k0 + BK, lB[nxt] + t * 16 + 4096);
    }
    i32x4 af[4], bfr[4];
#pragma unroll
    for (int m = 0; m < 4; ++m)
      af[m] = *(const i32x4*)(lA[cur] + (rA + m * 16) * BK + kr16);
#pragma unroll
    for (int n = 0; n < 4; ++n)
      bfr[n] = *(const i32x4*)(lB[cur] + (rB + n * 16) * BK + kr16);
    __builtin_amdgcn_s_setprio(1);
#pragma unroll
    for (int m = 0; m < 4; ++m)
#pragma unroll
      for (int n = 0; n < 4; ++n)
        acc[m][n] = __builtin_amdgcn_mfma_i32_16x16x64_i8(af[m], bfr[n], acc[m][n], 0, 0, 0);
    __builtin_amdgcn_s_setprio(0);
    __syncthreads();
    cur ^= 1;
  }

  const int cr = (lane >> 4) * 4;
  const int cc = lane & 15;
#pragma unroll
  for (int m = 0; m < 4; ++m) {
    const long r0 = m0 + wr * 64 + m * 16 + cr;
    const float s0 = srow[r0], s1 = srow[r0 + 1], s2 = srow[r0 + 2], s3 = srow[r0 + 3];
#pragma unroll
    for (int n = 0; n < 4; ++n) {
      const long col = n0 + wc * 64 + n * 16 + cc;
      const float wsC = wscale[col];
      const float bC = bias[col];
      float* o = C + r0 * N + col;
      o[0]      = (float)acc[m][n][0] * (s0 * wsC) + bC;
      o[N]      = (float)acc[m][n][1] * (s1 * wsC) + bC;
      o[2L * N] = (float)acc[m][n][2] * (s2 * wsC) + bC;
      o[3L * N] = (float)acc[m][n][3] * (s3 * wsC) + bC;
    }
  }
}

// ---------------------------------------------------------------------------
// fp32 -> bf16 convert (vectorized)
// ---------------------------------------------------------------------------
__global__ __launch_bounds__(256) void cvt_bf16(const float* __restrict__ in,
                                                __hip_bfloat16* __restrict__ out, int n4)
{
  const int i = blockIdx.x * 256 + threadIdx.x;
  if (i >= n4) return;
  f32x4 v = ((const f32x4*)in)[i];
  __hip_bfloat16 o[4];
#pragma unroll
  for (int j = 0; j < 4; ++j) o[j] = __float2bfloat16(v[j]);
  *(ushort4*)(out + i * 4L) = *(ushort4*)o;
}

// fp32 -> (hi, lo) bf16 split: hi = bf16(v), lo = bf16(v - hi)
__global__ __launch_bounds__(256) void cvt_split(const float* __restrict__ in,
                                                 __hip_bfloat16* __restrict__ hi,
                                                 __hip_bfloat16* __restrict__ lo, int n4)
{
  const int i = blockIdx.x * 256 + threadIdx.x;
  if (i >= n4) return;
  f32x4 v = ((const f32x4*)in)[i];
  __hip_bfloat16 oh[4], ol[4];
#pragma unroll
  for (int j = 0; j < 4; ++j) {
    oh[j] = __float2bfloat16(v[j]);
    ol[j] = __float2bfloat16(v[j] - __bfloat162float(oh[j]));
  }
  *(ushort4*)(hi + i * 4L) = *(ushort4*)oh;
  *(ushort4*)(lo + i * 4L) = *(ushort4*)ol;
}

// R[i][j] fp32 -> Sb[j][i] = sign(R[i][j]) as bf16 ±1 (tiled transpose).
__global__ __launch_bounds__(256) void transpose_sign(const float* __restrict__ in,
                                                      __hip_bfloat16* __restrict__ out, int N)
{
  __shared__ float tile[32][33];
  const int nb = N >> 5;
  const int bx = blockIdx.x % nb, by = blockIdx.x / nb;
  const int tx = threadIdx.x & 31, ty = threadIdx.x >> 5;  // ty 0..7
#pragma unroll
  for (int i = 0; i < 4; ++i)
    tile[ty + i * 8][tx] = in[(long)(by * 32 + ty + i * 8) * N + bx * 32 + tx];
  __syncthreads();
#pragma unroll
  for (int i = 0; i < 4; ++i) {
    const float v = tile[tx][ty + i * 8];
    const unsigned short s = (unsigned short)(0x3F80u | ((__float_as_uint(v) >> 16) & 0x8000u));
    *(unsigned short*)&out[(long)(bx * 32 + ty + i * 8) * N + by * 32 + tx] = s;
  }
}

// colf1[i] = cws[i]*r0 (for w_rot), colf2[i] = r0/cws[i] (for h), r0 = |R[0]|
__global__ __launch_bounds__(256) void make_colf(const float* __restrict__ cws,
                                                 const float* __restrict__ R,
                                                 float* __restrict__ colf1,
                                                 float* __restrict__ colf2, int n)
{
  const int i = blockIdx.x * 256 + threadIdx.x;
  const float r0 = fabsf(R[0]);
  if (i < n) {
    colf1[i] = cws[i] * r0;
    colf2[i] = r0 / cws[i];
  }
}

// ---------------------------------------------------------------------------
// Weight fake-quant -> i8 (q-8 in [-8,7]), one block per output row.
// ---------------------------------------------------------------------------
__global__ __launch_bounds__(256) void wquant(
    const float* __restrict__ wrot,
    const float* __restrict__ cfmax, const float* __restrict__ cfmin,
    char* __restrict__ qw, float* __restrict__ wscale)
{
  const int row = blockIdx.x;
  const float* w = wrot + (long)row * DIN;
  const int t = threadIdx.x;
  f32x4 v0 = ((const f32x4*)w)[t];
  f32x4 v1 = ((const f32x4*)w)[t + 256];
  float vmin = v0[0], vmax = v0[0];
#pragma unroll
  for (int j = 1; j < 4; ++j) { vmin = fminf(vmin, v0[j]); vmax = fmaxf(vmax, v0[j]); }
#pragma unroll
  for (int j = 0; j < 4; ++j) { vmin = fminf(vmin, v1[j]); vmax = fmaxf(vmax, v1[j]); }
#pragma unroll
  for (int off = 32; off; off >>= 1) {
    vmin = fminf(vmin, __shfl_xor(vmin, off));
    vmax = fmaxf(vmax, __shfl_xor(vmax, off));
  }
  __shared__ float smin[4], smax[4];
  const int lane = t & 63, wid = t >> 6;
  if (lane == 0) { smin[wid] = vmin; smax[wid] = vmax; }
  __syncthreads();
  vmin = fminf(fminf(smin[0], smin[1]), fminf(smin[2], smin[3]));
  vmax = fmaxf(fmaxf(smax[0], smax[1]), fmaxf(smax[2], smax[3]));

  const float sgmax = 1.f / (1.f + expf(-cfmax[row]));
  const float sgmin = 1.f / (1.f + expf(-cfmin[row]));
  const float wminc = vmin * sgmin;
  const float wmaxc = vmax * sgmax;
  float cmin = fminf(fmaxf(vmin, wminc), wmaxc);
  float cmax = fmaxf(fminf(vmax, wmaxc), wminc);
  float xmin = fminf(cmin, 0.f), xmax = fmaxf(cmax, 0.f);
  const float xm = fmaxf(fabsf(xmin), xmax);
  xmin = (xmin < 0.f) ? -xm : xmin;
  xmax = xm;
  if ((xmin == 0.f) && (xmax == 0.f)) { xmin = -1.f; xmax = 1.f; }
  const float scale = (xmax - xmin) / 15.f;
  if (t == 0) wscale[row] = scale;

  char* qr = qw + (long)row * DIN;
  i8x4 o0, o1;
#pragma unroll
  for (int j = 0; j < 4; ++j) {
    float wc = fminf(fmaxf(v0[j], wminc), wmaxc);
    float q = rintf(wc / scale) + 8.f;
    q = fminf(fmaxf(q, 0.f), 15.f);
    o0[j] = (char)(int)(q - 8.f);
    wc = fminf(fmaxf(v1[j], wminc), wmaxc);
    q = rintf(wc / scale) + 8.f;
    q = fminf(fmaxf(q, 0.f), 15.f);
    o1[j] = (char)(int)(q - 8.f);
  }
  *(i8x4*)(qr + t * 4) = o0;
  *(i8x4*)(qr + 1024 + t * 4) = o1;
}

// ---------------------------------------------------------------------------
// Activation fake-quant -> i8 (q in [-128,127]), one block per token (bf16 in).
// ---------------------------------------------------------------------------
__global__ __launch_bounds__(256) void hquant(
    const __hip_bfloat16* __restrict__ h,
    char* __restrict__ qh,
    float* __restrict__ srow)
{
  const long row = blockIdx.x;
  const __hip_bfloat16* hr = h + row * DIN;
  const int t = threadIdx.x;
  bf16x8 v = *(const bf16x8*)(hr + t * 8);
  float f[8];
  float amax = 0.f;
#pragma unroll
  for (int j = 0; j < 8; ++j) { f[j] = (float)v[j]; amax = fmaxf(amax, fabsf(f[j])); }
#pragma unroll
  for (int off = 32; off; off >>= 1) amax = fmaxf(amax, __shfl_xor(amax, off));
  __shared__ float sm[4];
  const int lane = t & 63, wid = t >> 6;
  if (lane == 0) sm[wid] = amax;
  __syncthreads();
  amax = fmaxf(fmaxf(sm[0], sm[1]), fmaxf(sm[2], sm[3]));
  const float s = fmaxf(amax / 127.f, 1e-8f);
  if (t == 0) srow[row] = s;
  const float is = 1.f / s;

  char o[8];
#pragma unroll
  for (int j = 0; j < 8; ++j) {
    float q = fminf(fmaxf(rintf(f[j] * is), -128.f), 127.f);
    o[j] = (char)(int)q;
  }
  *(uint2*)(qh + row * DIN + t * 8) = *(uint2*)o;
}

// ---------------------------------------------------------------------------
extern "C" void kernel_launch(void* const* d_in, const int* in_sizes, int n_in,
                              void* d_out, int out_size, void* d_ws, size_t ws_size,
                              hipStream_t stream)
{
  const float* X     = (const float*)d_in[0];  // [4,4096,2048]
  const float* W     = (const float*)d_in[1];  // [2048,2048]
  const float* bias  = (const float*)d_in[2];  // [2048]
  const float* R     = (const float*)d_in[3];  // [2048,2048]
  const float* cws   = (const float*)d_in[4];  // [1,2048]
  const float* cfmax = (const float*)d_in[5];  // [2048,1]
  const float* cfmin = (const float*)d_in[6];  // [2048,1]
  float* out = (float*)d_out;

  // d_out (134 MB) doubles as scratch:
  //   wrot f32 (16 MB) @ +0        live GEMM1 -> wquant
  //   Wlo  bf16 (8 MB) @ +16MB     live cvt   -> GEMM1
  //   h    bf16 (67 MB) @ +0       live GEMM2 -> hquant (overwrites all)
  float*          wrot = (float*)d_out;
  __hip_bfloat16* Wlo  = (__hip_bfloat16*)((char*)d_out + (size_t)DOUT * DIN * 4);
  __hip_bfloat16* h    = (__hip_bfloat16*)d_out;

  char* ws = (char*)d_ws;
  size_t off = 0;
  auto alloc = [&](size_t bytes) -> void* {
    void* p = ws + off;
    off += (bytes + 255) & ~(size_t)255;
    return p;
  };
  __hip_bfloat16* Xb    = (__hip_bfloat16*)alloc((size_t)NTOK * DIN * 2);  // bf16 X
  __hip_bfloat16* Sb    = (__hip_bfloat16*)alloc((size_t)DIN * DIN * 2);   // sign(R)^T, ±1
  __hip_bfloat16* Whi   = (__hip_bfloat16*)alloc((size_t)DOUT * DIN * 2);
  char*           qh    = (char*)alloc((size_t)NTOK * DIN);                // i8 activations
  char*           qw    = (char*)alloc((size_t)DOUT * DIN);                // i8 weights (q-8)
  float*          wsc   = (float*)alloc(DOUT * 4);
  float*          srow  = (float*)alloc(NTOK * 4);
  float*          colf1 = (float*)alloc(DIN * 4);
  float*          colf2 = (float*)alloc(DIN * 4);

  // 1. converts
  cvt_bf16<<<(NTOK * DIN / 4 + 255) / 256, 256, 0, stream>>>(X, Xb, NTOK * DIN / 4);
  cvt_split<<<(DOUT * DIN / 4 + 255) / 256, 256, 0, stream>>>(W, Whi, Wlo, DOUT * DIN / 4);
  transpose_sign<<<(DIN / 32) * (DIN / 32), 256, 0, stream>>>(R, Sb, DIN);
  make_colf<<<(DIN + 255) / 256, 256, 0, stream>>>(cws, R, colf1, colf2, DIN);

  // 2. w_rot = r0*(W@S) * cws -> fp32 (d_out scratch)
  gemm_wsplit2<<<(DOUT / 128) * (DIN / 64), 256, 0, stream>>>(
      Whi, Wlo, Sb, wrot, colf1, DOUT, DIN, DIN);

  // 3. weight fake-quant -> qw (i8), wscale
  wquant<<<DOUT, 256, 0, stream>>>(wrot, cfmax, cfmin, qw, wsc);

  // 4. h = r0*(X@S) / cws -> bf16 (d_out scratch; wrot/Wlo now dead)
  gemm_bt<__hip_bfloat16><<<(NTOK / 128) * (DIN / 128), 256, 0, stream>>>(
      Xb, Sb, h, colf2, NTOK, DIN, DIN);

  // 5. act fake-quant -> qh (i8), srow
  hquant<<<NTOK, 256, 0, stream>>>(h, qh, srow);

  // 6. out = qh @ qw^T * (srow*wscale) + bias   (i8 MFMA, exact)
  gemm_out_i8<<<(NTOK / 128) * (DOUT / 128), 256, 0, stream>>>(
      qh, qw, out, srow, wsc, bias, NTOK, DOUT, DIN);
}

// Round 8
// 575.720 us; speedup vs baseline: 1.2802x; 1.0305x over previous
//
#include <hip/hip_runtime.h>
#include <hip/hip_bf16.h>

#define DIN 2048
#define DOUT 2048
#define NTOK 16384   // B*S = 4*4096

typedef __bf16 bf16x8 __attribute__((ext_vector_type(8)));
typedef float f32x4 __attribute__((ext_vector_type(4)));
typedef int   i32x4 __attribute__((ext_vector_type(4)));
typedef char  i8x4  __attribute__((ext_vector_type(4)));

#define VMCNT4 asm volatile("s_waitcnt vmcnt(4)" ::: "memory")
#define VMCNT5 asm volatile("s_waitcnt vmcnt(5)" ::: "memory")
#define VMCNT0 asm volatile("s_waitcnt vmcnt(0)" ::: "memory")
#define SCHEDB __builtin_amdgcn_sched_barrier(0)
#define BARRIER __builtin_amdgcn_s_barrier()

__device__ __forceinline__ void load_lds16(const void* g, void* l) {
  __builtin_amdgcn_global_load_lds((const __attribute__((address_space(1))) void*)g,
                                   (__attribute__((address_space(3))) void*)l,
                                   16, 0, 0);
}

__device__ __forceinline__ void store1(float* p, float v) { *p = v; }
__device__ __forceinline__ void store1(__hip_bfloat16* p, float v) { *p = __float2bfloat16(v); }

// XCD-aware bijective block swizzle (nwg % 8 == 0)
__device__ __forceinline__ int xcd_swz(int bid, int nwg) {
  const int cpx = nwg >> 3;
  return (bid & 7) * cpx + (bid >> 3);
}

// LDS bank swizzle (tiles with 64-B rows, 16-B chunks):
//   forward (read side):  lds_byte = (row*64 + g*16) ^ ((row&7)<<4)
//   inverse (stage side): slot s=(R,G) holds chunk row=(R&~1)|((R&1)^((R>>2)&1)),
//                         g = G ^ (row&3)
// Quarter-wave bank-quad coverage goes {0,4} 8-way -> all 8 quads 2-way (free).
__device__ __forceinline__ int swz_row(int slot) {
  const int R = slot >> 2;
  return (R & ~1) | ((R & 1) ^ ((R >> 2) & 1));
}

// ---------------------------------------------------------------------------
// C[m][n] = (sum_k A[m][k]*B[n][k]) * colf[n]    (B^T GEMM, bf16 in, fp32 acc)
// 128x128 tile, BK=32, 4 waves; 3-buffer counted-vmcnt pipeline + LDS swizzle.
// ---------------------------------------------------------------------------
template <typename OutT>
__global__ __launch_bounds__(256) void gemm_bt(
    const __hip_bfloat16* __restrict__ A,
    const __hip_bfloat16* __restrict__ B,
    OutT* __restrict__ C,
    const float* __restrict__ colf,
    int M, int N, int K)
{
  constexpr int BK = 32;           // elements per K-step
  constexpr int STRIDE = 16384;    // bytes per buffer (A 8K + B 8K)
  __shared__ char lds[3 * STRIDE];
  const int t = threadIdx.x;
  const int lane = t & 63;
  const int wid = t >> 6;
  const int wr = wid >> 1, wc = wid & 1;
  const int nbn = N / 128;
  const int bid = xcd_swz(blockIdx.x, gridDim.x);
  const long m0 = (long)(bid / nbn) * 128;
  const long n0 = (long)(bid % nbn) * 128;
  const int NT = K / BK;

  // staging: slot t -> swizzled source (row, chunk)
  const int orow = swz_row(t);
  const int og   = (t & 3) ^ (orow & 3);
  const int ldst = t * 16;

  const __hip_bfloat16* gA0 = A + (m0 + orow) * (long)K + og * 8;
  const __hip_bfloat16* gA1 = gA0 + 64L * K;
  const __hip_bfloat16* gB0 = B + (n0 + orow) * (long)K + og * 8;
  const __hip_bfloat16* gB1 = gB0 + 64L * K;

  f32x4 acc[4][4] = {};

  const int g16 = (lane >> 4) * 16;
  const int swzm = (lane & 7) << 4;
  const int rA = wr * 64 + (lane & 15);
  const int rB = wc * 64 + (lane & 15);
  const int aOff = (rA * 64 + g16) ^ swzm;           // byte offset in A half
  const int bOff = 8192 + ((rB * 64 + g16) ^ swzm);  // byte offset in B half

  char* pc = lds;
  char* pn = lds + STRIDE;
  char* pf = lds + 2 * STRIDE;

#define GBT_ISSUE(buf, kOff)                                   \
  do {                                                         \
    load_lds16(gA0 + (kOff), (buf) + ldst);                    \
    load_lds16(gA1 + (kOff), (buf) + 4096 + ldst);             \
    load_lds16(gB0 + (kOff), (buf) + 8192 + ldst);             \
    load_lds16(gB1 + (kOff), (buf) + 8192 + 4096 + ldst);      \
  } while (0)

  // prologue: tiles 0 and 1
  GBT_ISSUE(pc, 0);
  GBT_ISSUE(pn, BK);
  VMCNT4; SCHEDB; BARRIER; SCHEDB;

  for (int tt = 0; tt < NT; ++tt) {
    if (tt + 2 < NT) GBT_ISSUE(pf, (tt + 2) * BK);
    bf16x8 af[4], bfr[4];
#pragma unroll
    for (int m = 0; m < 4; ++m)
      af[m] = *(const bf16x8*)(pc + aOff + m * 1024);
#pragma unroll
    for (int n = 0; n < 4; ++n)
      bfr[n] = *(const bf16x8*)(pc + bOff + n * 1024);
    __builtin_amdgcn_s_setprio(1);
#pragma unroll
    for (int m = 0; m < 4; ++m)
#pragma unroll
      for (int n = 0; n < 4; ++n)
        acc[m][n] = __builtin_amdgcn_mfma_f32_16x16x32_bf16(af[m], bfr[n], acc[m][n], 0, 0, 0);
    __builtin_amdgcn_s_setprio(0);
    if (tt < NT - 1) {
      if (tt < NT - 2) { VMCNT4; } else { VMCNT0; }
      SCHEDB; BARRIER; SCHEDB;
    }
    char* tmp = pc; pc = pn; pn = pf; pf = tmp;
  }
#undef GBT_ISSUE

  // C/D layout: col = lane&15, row = (lane>>4)*4 + e
  const int cr = (lane >> 4) * 4;
  const int cc = lane & 15;
#pragma unroll
  for (int m = 0; m < 4; ++m) {
    const long r0 = m0 + wr * 64 + m * 16 + cr;
#pragma unroll
    for (int n = 0; n < 4; ++n) {
      const long col = n0 + wc * 64 + n * 16 + cc;
      const float f = colf[col];
#pragma unroll
      for (int e = 0; e < 4; ++e)
        store1(&C[(r0 + e) * N + col], acc[m][n][e] * f);
    }
  }
}

// ---------------------------------------------------------------------------
// w_rot = (Whi + Wlo) @ S * colf  -- S exact ±1 sign matrix (B^T form).
// Tile 128x64, BK=32; 3-buffer counted-vmcnt pipeline + LDS swizzle.
// ---------------------------------------------------------------------------
__global__ __launch_bounds__(256) void gemm_wsplit2(
    const __hip_bfloat16* __restrict__ Ahi, const __hip_bfloat16* __restrict__ Alo,
    const __hip_bfloat16* __restrict__ Bs,
    float* __restrict__ C,
    const float* __restrict__ colf,
    int M, int N, int K)
{
  constexpr int BK = 32;
  constexpr int STRIDE = 20480;   // Ahi 8K + Alo 8K + B 4K
  __shared__ char lds[3 * STRIDE];
  const int t = threadIdx.x;
  const int lane = t & 63;
  const int wid = t >> 6;
  const int wr = wid >> 1, wc = wid & 1;
  const int nbn = N / 64;
  const int bid = xcd_swz(blockIdx.x, gridDim.x);
  const long m0 = (long)(bid / nbn) * 128;
  const long n0 = (long)(bid % nbn) * 64;
  const int NT = K / BK;

  const int orow = swz_row(t);
  const int og   = (t & 3) ^ (orow & 3);
  const int ldst = t * 16;

  const __hip_bfloat16* gH0 = Ahi + (m0 + orow) * (long)K + og * 8;
  const __hip_bfloat16* gH1 = gH0 + 64L * K;
  const __hip_bfloat16* gL0 = Alo + (m0 + orow) * (long)K + og * 8;
  const __hip_bfloat16* gL1 = gL0 + 64L * K;
  const __hip_bfloat16* gS  = Bs + (n0 + orow) * (long)K + og * 8;

  f32x4 acc[4][2] = {};

  const int g16 = (lane >> 4) * 16;
  const int swzm = (lane & 7) << 4;
  const int rA = wr * 64 + (lane & 15);
  const int rB = wc * 32 + (lane & 15);
  const int aOff = (rA * 64 + g16) ^ swzm;            // within Ahi block
  const int bOff = 16384 + ((rB * 64 + g16) ^ swzm);  // B block

  char* pc = lds;
  char* pn = lds + STRIDE;
  char* pf = lds + 2 * STRIDE;

#define WSP_ISSUE(buf, kOff)                                    \
  do {                                                          \
    load_lds16(gH0 + (kOff), (buf) + ldst);                     \
    load_lds16(gH1 + (kOff), (buf) + 4096 + ldst);              \
    load_lds16(gL0 + (kOff), (buf) + 8192 + ldst);              \
    load_lds16(gL1 + (kOff), (buf) + 8192 + 4096 + ldst);       \
    load_lds16(gS + (kOff), (buf) + 16384 + ldst);              \
  } while (0)

  WSP_ISSUE(pc, 0);
  WSP_ISSUE(pn, BK);
  VMCNT5; SCHEDB; BARRIER; SCHEDB;

  for (int tt = 0; tt < NT; ++tt) {
    if (tt + 2 < NT) WSP_ISSUE(pf, (tt + 2) * BK);
    bf16x8 ah[4], al[4], bs[2];
#pragma unroll
    for (int m = 0; m < 4; ++m) {
      ah[m] = *(const bf16x8*)(pc + aOff + m * 1024);
      al[m] = *(const bf16x8*)(pc + 8192 + aOff + m * 1024);
    }
#pragma unroll
    for (int n = 0; n < 2; ++n)
      bs[n] = *(const bf16x8*)(pc + bOff + n * 1024);
    __builtin_amdgcn_s_setprio(1);
#pragma unroll
    for (int m = 0; m < 4; ++m)
#pragma unroll
      for (int n = 0; n < 2; ++n) {
        acc[m][n] = __builtin_amdgcn_mfma_f32_16x16x32_bf16(ah[m], bs[n], acc[m][n], 0, 0, 0);
        acc[m][n] = __builtin_amdgcn_mfma_f32_16x16x32_bf16(al[m], bs[n], acc[m][n], 0, 0, 0);
      }
    __builtin_amdgcn_s_setprio(0);
    if (tt < NT - 1) {
      if (tt < NT - 2) { VMCNT5; } else { VMCNT0; }
      SCHEDB; BARRIER; SCHEDB;
    }
    char* tmp = pc; pc = pn; pn = pf; pf = tmp;
  }
#undef WSP_ISSUE

  const int cr = (lane >> 4) * 4;
  const int cc = lane & 15;
#pragma unroll
  for (int m = 0; m < 4; ++m) {
    const long r0 = m0 + wr * 64 + m * 16 + cr;
#pragma unroll
    for (int n = 0; n < 2; ++n) {
      const long col = n0 + wc * 32 + n * 16 + cc;
      const float f = colf[col];
#pragma unroll
      for (int e = 0; e < 4; ++e)
        C[(r0 + e) * N + col] = acc[m][n][e] * f;
    }
  }
}

// ---------------------------------------------------------------------------
// Final GEMM in i8 (exact): out = (qh @ qw^T) * srow*wscale + bias
// 128x128 tile, BK=64 bytes; 3-buffer counted-vmcnt pipeline + LDS swizzle.
// ---------------------------------------------------------------------------
__global__ __launch_bounds__(256) void gemm_out_i8(
    const char* __restrict__ A,
    const char* __restrict__ B,
    float* __restrict__ C,
    const float* __restrict__ srow,
    const float* __restrict__ wscale,
    const float* __restrict__ bias,
    int M, int N, int K)
{
  constexpr int BK = 64;           // bytes == elements per K-step
  constexpr int STRIDE = 16384;
  __shared__ char lds[3 * STRIDE];
  const int t = threadIdx.x;
  const int lane = t & 63;
  const int wid = t >> 6;
  const int wr = wid >> 1, wc = wid & 1;
  const int nbn = N / 128;
  const int bid = xcd_swz(blockIdx.x, gridDim.x);
  const long m0 = (long)(bid / nbn) * 128;
  const long n0 = (long)(bid % nbn) * 128;
  const int NT = K / BK;

  const int orow = swz_row(t);
  const int og   = (t & 3) ^ (orow & 3);
  const int ldst = t * 16;

  const char* gA0 = A + (m0 + orow) * (long)K + og * 16;
  const char* gA1 = gA0 + 64L * K;
  const char* gB0 = B + (n0 + orow) * (long)K + og * 16;
  const char* gB1 = gB0 + 64L * K;

  i32x4 acc[4][4] = {};

  const int g16 = (lane >> 4) * 16;
  const int swzm = (lane & 7) << 4;
  const int rA = wr * 64 + (lane & 15);
  const int rB = wc * 64 + (lane & 15);
  const int aOff = (rA * 64 + g16) ^ swzm;
  const int bOff = 8192 + ((rB * 64 + g16) ^ swzm);

  char* pc = lds;
  char* pn = lds + STRIDE;
  char* pf = lds + 2 * STRIDE;

#define GI8_ISSUE(buf, kOff)                                   \
  do {                                                         \
    load_lds16(gA0 + (kOff), (buf) + ldst);                    \
    load_lds16(gA1 + (kOff), (buf) + 4096 + ldst);             \
    load_lds16(gB0 + (kOff), (buf) + 8192 + ldst);             \
    load_lds16(gB1 + (kOff), (buf) + 8192 + 4096 + ldst);      \
  } while (0)

  GI8_ISSUE(pc, 0);
  GI8_ISSUE(pn, BK);
  VMCNT4; SCHEDB; BARRIER; SCHEDB;

  for (int tt = 0; tt < NT; ++tt) {
    if (tt + 2 < NT) GI8_ISSUE(pf, (tt + 2) * BK);
    i32x4 af[4], bfr[4];
#pragma unroll
    for (int m = 0; m < 4; ++m)
      af[m] = *(const i32x4*)(pc + aOff + m * 1024);
#pragma unroll
    for (int n = 0; n < 4; ++n)
      bfr[n] = *(const i32x4*)(pc + bOff + n * 1024);
    __builtin_amdgcn_s_setprio(1);
#pragma unroll
    for (int m = 0; m < 4; ++m)
#pragma unroll
      for (int n = 0; n < 4; ++n)
        acc[m][n] = __builtin_amdgcn_mfma_i32_16x16x64_i8(af[m], bfr[n], acc[m][n], 0, 0, 0);
    __builtin_amdgcn_s_setprio(0);
    if (tt < NT - 1) {
      if (tt < NT - 2) { VMCNT4; } else { VMCNT0; }
      SCHEDB; BARRIER; SCHEDB;
    }
    char* tmp = pc; pc = pn; pn = pf; pf = tmp;
  }
#undef GI8_ISSUE

  const int cr = (lane >> 4) * 4;
  const int cc = lane & 15;
#pragma unroll
  for (int m = 0; m < 4; ++m) {
    const long r0 = m0 + wr * 64 + m * 16 + cr;
    const float s0 = srow[r0], s1 = srow[r0 + 1], s2 = srow[r0 + 2], s3 = srow[r0 + 3];
#pragma unroll
    for (int n = 0; n < 4; ++n) {
      const long col = n0 + wc * 64 + n * 16 + cc;
      const float wsC = wscale[col];
      const float bC = bias[col];
      float* o = C + r0 * N + col;
      o[0]      = (float)acc[m][n][0] * (s0 * wsC) + bC;
      o[N]      = (float)acc[m][n][1] * (s1 * wsC) + bC;
      o[2L * N] = (float)acc[m][n][2] * (s2 * wsC) + bC;
      o[3L * N] = (float)acc[m][n][3] * (s3 * wsC) + bC;
    }
  }
}

// ---------------------------------------------------------------------------
// fp32 -> bf16 convert (vectorized)
// ---------------------------------------------------------------------------
__global__ __launch_bounds__(256) void cvt_bf16(const float* __restrict__ in,
                                                __hip_bfloat16* __restrict__ out, int n4)
{
  const int i = blockIdx.x * 256 + threadIdx.x;
  if (i >= n4) return;
  f32x4 v = ((const f32x4*)in)[i];
  __hip_bfloat16 o[4];
#pragma unroll
  for (int j = 0; j < 4; ++j) o[j] = __float2bfloat16(v[j]);
  *(ushort4*)(out + i * 4L) = *(ushort4*)o;
}

// fp32 -> (hi, lo) bf16 split: hi = bf16(v), lo = bf16(v - hi)
__global__ __launch_bounds__(256) void cvt_split(const float* __restrict__ in,
                                                 __hip_bfloat16* __restrict__ hi,
                                                 __hip_bfloat16* __restrict__ lo, int n4)
{
  const int i = blockIdx.x * 256 + threadIdx.x;
  if (i >= n4) return;
  f32x4 v = ((const f32x4*)in)[i];
  __hip_bfloat16 oh[4], ol[4];
#pragma unroll
  for (int j = 0; j < 4; ++j) {
    oh[j] = __float2bfloat16(v[j]);
    ol[j] = __float2bfloat16(v[j] - __bfloat162float(oh[j]));
  }
  *(ushort4*)(hi + i * 4L) = *(ushort4*)oh;
  *(ushort4*)(lo + i * 4L) = *(ushort4*)ol;
}

// R[i][j] fp32 -> Sb[j][i] = sign(R[i][j]) as bf16 ±1 (tiled transpose).
__global__ __launch_bounds__(256) void transpose_sign(const float* __restrict__ in,
                                                      __hip_bfloat16* __restrict__ out, int N)
{
  __shared__ float tile[32][33];
  const int nb = N >> 5;
  const int bx = blockIdx.x % nb, by = blockIdx.x / nb;
  const int tx = threadIdx.x & 31, ty = threadIdx.x >> 5;  // ty 0..7
#pragma unroll
  for (int i = 0; i < 4; ++i)
    tile[ty + i * 8][tx] = in[(long)(by * 32 + ty + i * 8) * N + bx * 32 + tx];
  __syncthreads();
#pragma unroll
  for (int i = 0; i < 4; ++i) {
    const float v = tile[tx][ty + i * 8];
    const unsigned short s = (unsigned short)(0x3F80u | ((__float_as_uint(v) >> 16) & 0x8000u));
    *(unsigned short*)&out[(long)(bx * 32 + ty + i * 8) * N + by * 32 + tx] = s;
  }
}

// colf1[i] = cws[i]*r0 (for w_rot), colf2[i] = r0/cws[i] (for h), r0 = |R[0]|
__global__ __launch_bounds__(256) void make_colf(const float* __restrict__ cws,
                                                 const float* __restrict__ R,
                                                 float* __restrict__ colf1,
                                                 float* __restrict__ colf2, int n)
{
  const int i = blockIdx.x * 256 + threadIdx.x;
  const float r0 = fabsf(R[0]);
  if (i < n) {
    colf1[i] = cws[i] * r0;
    colf2[i] = r0 / cws[i];
  }
}

// ---------------------------------------------------------------------------
// Weight fake-quant -> i8 (q-8 in [-8,7]), one block per output row.
// ---------------------------------------------------------------------------
__global__ __launch_bounds__(256) void wquant(
    const float* __restrict__ wrot,
    const float* __restrict__ cfmax, const float* __restrict__ cfmin,
    char* __restrict__ qw, float* __restrict__ wscale)
{
  const int row = blockIdx.x;
  const float* w = wrot + (long)row * DIN;
  const int t = threadIdx.x;
  f32x4 v0 = ((const f32x4*)w)[t];
  f32x4 v1 = ((const f32x4*)w)[t + 256];
  float vmin = v0[0], vmax = v0[0];
#pragma unroll
  for (int j = 1; j < 4; ++j) { vmin = fminf(vmin, v0[j]); vmax = fmaxf(vmax, v0[j]); }
#pragma unroll
  for (int j = 0; j < 4; ++j) { vmin = fminf(vmin, v1[j]); vmax = fmaxf(vmax, v1[j]); }
#pragma unroll
  for (int off = 32; off; off >>= 1) {
    vmin = fminf(vmin, __shfl_xor(vmin, off));
    vmax = fmaxf(vmax, __shfl_xor(vmax, off));
  }
  __shared__ float smin[4], smax[4];
  const int lane = t & 63, wid = t >> 6;
  if (lane == 0) { smin[wid] = vmin; smax[wid] = vmax; }
  __syncthreads();
  vmin = fminf(fminf(smin[0], smin[1]), fminf(smin[2], smin[3]));
  vmax = fmaxf(fmaxf(smax[0], smax[1]), fmaxf(smax[2], smax[3]));

  const float sgmax = 1.f / (1.f + expf(-cfmax[row]));
  const float sgmin = 1.f / (1.f + expf(-cfmin[row]));
  const float wminc = vmin * sgmin;
  const float wmaxc = vmax * sgmax;
  float cmin = fminf(fmaxf(vmin, wminc), wmaxc);
  float cmax = fmaxf(fminf(vmax, wmaxc), wminc);
  float xmin = fminf(cmin, 0.f), xmax = fmaxf(cmax, 0.f);
  const float xm = fmaxf(fabsf(xmin), xmax);
  xmin = (xmin < 0.f) ? -xm : xmin;
  xmax = xm;
  if ((xmin == 0.f) && (xmax == 0.f)) { xmin = -1.f; xmax = 1.f; }
  const float scale = (xmax - xmin) / 15.f;
  if (t == 0) wscale[row] = scale;

  char* qr = qw + (long)row * DIN;
  i8x4 o0, o1;
#pragma unroll
  for (int j = 0; j < 4; ++j) {
    float wc = fminf(fmaxf(v0[j], wminc), wmaxc);
    float q = rintf(wc / scale) + 8.f;
    q = fminf(fmaxf(q, 0.f), 15.f);
    o0[j] = (char)(int)(q - 8.f);
    wc = fminf(fmaxf(v1[j], wminc), wmaxc);
    q = rintf(wc / scale) + 8.f;
    q = fminf(fmaxf(q, 0.f), 15.f);
    o1[j] = (char)(int)(q - 8.f);
  }
  *(i8x4*)(qr + t * 4) = o0;
  *(i8x4*)(qr + 1024 + t * 4) = o1;
}

// ---------------------------------------------------------------------------
// Activation fake-quant -> i8 (q in [-128,127]), one block per token (bf16 in).
// ---------------------------------------------------------------------------
__global__ __launch_bounds__(256) void hquant(
    const __hip_bfloat16* __restrict__ h,
    char* __restrict__ qh,
    float* __restrict__ srow)
{
  const long row = blockIdx.x;
  const __hip_bfloat16* hr = h + row * DIN;
  const int t = threadIdx.x;
  bf16x8 v = *(const bf16x8*)(hr + t * 8);
  float f[8];
  float amax = 0.f;
#pragma unroll
  for (int j = 0; j < 8; ++j) { f[j] = (float)v[j]; amax = fmaxf(amax, fabsf(f[j])); }
#pragma unroll
  for (int off = 32; off; off >>= 1) amax = fmaxf(amax, __shfl_xor(amax, off));
  __shared__ float sm[4];
  const int lane = t & 63, wid = t >> 6;
  if (lane == 0) sm[wid] = amax;
  __syncthreads();
  amax = fmaxf(fmaxf(sm[0], sm[1]), fmaxf(sm[2], sm[3]));
  const float s = fmaxf(amax / 127.f, 1e-8f);
  if (t == 0) srow[row] = s;
  const float is = 1.f / s;

  char o[8];
#pragma unroll
  for (int j = 0; j < 8; ++j) {
    float q = fminf(fmaxf(rintf(f[j] * is), -128.f), 127.f);
    o[j] = (char)(int)q;
  }
  *(uint2*)(qh + row * DIN + t * 8) = *(uint2*)o;
}

// ---------------------------------------------------------------------------
extern "C" void kernel_launch(void* const* d_in, const int* in_sizes, int n_in,
                              void* d_out, int out_size, void* d_ws, size_t ws_size,
                              hipStream_t stream)
{
  const float* X     = (const float*)d_in[0];  // [4,4096,2048]
  const float* W     = (const float*)d_in[1];  // [2048,2048]
  const float* bias  = (const float*)d_in[2];  // [2048]
  const float* R     = (const float*)d_in[3];  // [2048,2048]
  const float* cws   = (const float*)d_in[4];  // [1,2048]
  const float* cfmax = (const float*)d_in[5];  // [2048,1]
  const float* cfmin = (const float*)d_in[6];  // [2048,1]
  float* out = (float*)d_out;

  // d_out (134 MB) doubles as scratch:
  //   wrot f32 (16 MB) @ +0        live GEMM1 -> wquant
  //   Wlo  bf16 (8 MB) @ +16MB     live cvt   -> GEMM1
  //   h    bf16 (67 MB) @ +0       live GEMM2 -> hquant (overwrites all)
  float*          wrot = (float*)d_out;
  __hip_bfloat16* Wlo  = (__hip_bfloat16*)((char*)d_out + (size_t)DOUT * DIN * 4);
  __hip_bfloat16* h    = (__hip_bfloat16*)d_out;

  char* ws = (char*)d_ws;
  size_t off = 0;
  auto alloc = [&](size_t bytes) -> void* {
    void* p = ws + off;
    off += (bytes + 255) & ~(size_t)255;
    return p;
  };
  __hip_bfloat16* Xb    = (__hip_bfloat16*)alloc((size_t)NTOK * DIN * 2);  // bf16 X
  __hip_bfloat16* Sb    = (__hip_bfloat16*)alloc((size_t)DIN * DIN * 2);   // sign(R)^T, ±1
  __hip_bfloat16* Whi   = (__hip_bfloat16*)alloc((size_t)DOUT * DIN * 2);
  char*           qh    = (char*)alloc((size_t)NTOK * DIN);                // i8 activations
  char*           qw    = (char*)alloc((size_t)DOUT * DIN);                // i8 weights (q-8)
  float*          wsc   = (float*)alloc(DOUT * 4);
  float*          srow  = (float*)alloc(NTOK * 4);
  float*          colf1 = (float*)alloc(DIN * 4);
  float*          colf2 = (float*)alloc(DIN * 4);

  // 1. converts
  cvt_bf16<<<(NTOK * DIN / 4 + 255) / 256, 256, 0, stream>>>(X, Xb, NTOK * DIN / 4);
  cvt_split<<<(DOUT * DIN / 4 + 255) / 256, 256, 0, stream>>>(W, Whi, Wlo, DOUT * DIN / 4);
  transpose_sign<<<(DIN / 32) * (DIN / 32), 256, 0, stream>>>(R, Sb, DIN);
  make_colf<<<(DIN + 255) / 256, 256, 0, stream>>>(cws, R, colf1, colf2, DIN);

  // 2. w_rot = r0*(W@S) * cws -> fp32 (d_out scratch)
  gemm_wsplit2<<<(DOUT / 128) * (DIN / 64), 256, 0, stream>>>(
      Whi, Wlo, Sb, wrot, colf1, DOUT, DIN, DIN);

  // 3. weight fake-quant -> qw (i8), wscale
  wquant<<<DOUT, 256, 0, stream>>>(wrot, cfmax, cfmin, qw, wsc);

  // 4. h = r0*(X@S) / cws -> bf16 (d_out scratch; wrot/Wlo now dead)
  gemm_bt<__hip_bfloat16><<<(NTOK / 128) * (DIN / 128), 256, 0, stream>>>(
      Xb, Sb, h, colf2, NTOK, DIN, DIN);

  // 5. act fake-quant -> qh (i8), srow
  hquant<<<NTOK, 256, 0, stream>>>(h, qh, srow);

  // 6. out = qh @ qw^T * (srow*wscale) + bias   (i8 MFMA, exact)
  gemm_out_i8<<<(NTOK / 128) * (DOUT / 128), 256, 0, stream>>>(
      qh, qw, out, srow, wsc, bias, NTOK, DOUT, DIN);
}